// Round 1
// baseline (787.445 us; speedup 1.0000x reference)
//
#include <hip/hip_runtime.h>
#include <cstdint>
#include <cstddef>

#define B_ 8
#define D_ 512
#define L_ 2048
#define C_ 256

// ---------------------------------------------------------------------------
// Kernel 1: fused QKV projection. z = b*3 + {q,k,v}. Y = W (C x D) * x1[b] (D x L) + bias
// 128x128 tile, BK=8, 256 threads, 8x8 microtile (4+4 column/row split).
// ---------------------------------------------------------------------------
__global__ __launch_bounds__(256) void qkv_kernel(
    const float* __restrict__ x1,
    const float* __restrict__ Wq, const float* __restrict__ bq,
    const float* __restrict__ Wk, const float* __restrict__ bk,
    const float* __restrict__ Wv, const float* __restrict__ bv,
    float* __restrict__ q, float* __restrict__ k, float* __restrict__ v)
{
  const int z = blockIdx.z;
  const int b = z / 3, w = z % 3;
  const float* W; const float* bias; float* outp;
  if (w == 0)      { W = Wq; bias = bq; outp = q; }
  else if (w == 1) { W = Wk; bias = bk; outp = k; }
  else             { W = Wv; bias = bv; outp = v; }

  const int m0 = blockIdx.y * 128;
  const int n0 = blockIdx.x * 128;
  const int tid = threadIdx.x;
  const int tm = tid >> 4, tn = tid & 15;

  __shared__ float As[8][128];  // [k][m] (transposed store)
  __shared__ float Bs[8][128];  // [k][n]

  float acc[8][8] = {};
  const int am = tid >> 1, ak = (tid & 1) * 4;
  const int bkk = tid >> 5, bl = (tid & 31) * 4;
  const float* xb = x1 + (size_t)b * D_ * L_;

  for (int k0 = 0; k0 < D_; k0 += 8) {
    float4 av  = *(const float4*)&W[(size_t)(m0 + am) * D_ + k0 + ak];
    float4 bv4 = *(const float4*)&xb[(size_t)(k0 + bkk) * L_ + n0 + bl];
    __syncthreads();
    As[ak+0][am] = av.x; As[ak+1][am] = av.y; As[ak+2][am] = av.z; As[ak+3][am] = av.w;
    *(float4*)&Bs[bkk][bl] = bv4;
    __syncthreads();
#pragma unroll
    for (int kk = 0; kk < 8; ++kk) {
      float4 a0 = *(const float4*)&As[kk][tm*4];
      float4 a1 = *(const float4*)&As[kk][tm*4+64];
      float4 b0 = *(const float4*)&Bs[kk][tn*4];
      float4 b1 = *(const float4*)&Bs[kk][tn*4+64];
      float a[8]  = {a0.x,a0.y,a0.z,a0.w,a1.x,a1.y,a1.z,a1.w};
      float bb[8] = {b0.x,b0.y,b0.z,b0.w,b1.x,b1.y,b1.z,b1.w};
#pragma unroll
      for (int i = 0; i < 8; ++i)
#pragma unroll
        for (int j = 0; j < 8; ++j)
          acc[i][j] += a[i] * bb[j];
    }
  }
  float* ob = outp + (size_t)b * C_ * L_;
#pragma unroll
  for (int i = 0; i < 8; ++i) {
    int r = m0 + ((i < 4) ? (tm*4 + i) : (64 + tm*4 + (i - 4)));
    float bs = bias[r];
    float4 v0 = make_float4(acc[i][0]+bs, acc[i][1]+bs, acc[i][2]+bs, acc[i][3]+bs);
    float4 v1 = make_float4(acc[i][4]+bs, acc[i][5]+bs, acc[i][6]+bs, acc[i][7]+bs);
    *(float4*)&ob[(size_t)r * L_ + n0 + tn*4]      = v0;
    *(float4*)&ob[(size_t)r * L_ + n0 + tn*4 + 64] = v1;
  }
}

// ---------------------------------------------------------------------------
// Kernel 2: S[l,m] = (sum_c q[c,l]*k[c,m]) * (1/16) + log(mask[m]+1e-6)
// Contraction dim c is the row index of both operands -> direct [k][spatial] staging.
// ---------------------------------------------------------------------------
__global__ __launch_bounds__(256) void s_kernel(
    const float* __restrict__ q, const float* __restrict__ kten,
    const float* __restrict__ mask, float* __restrict__ att, int bbase)
{
  const int bz = blockIdx.z, b = bbase + bz;
  const int l0 = blockIdx.y * 128;   // query rows
  const int m0 = blockIdx.x * 128;   // key cols
  const int tid = threadIdx.x;
  const int tm = tid >> 4, tn = tid & 15;

  __shared__ float As[8][128];
  __shared__ float Bs[8][128];
  float acc[8][8] = {};

  const int kk = tid >> 5, lq = (tid & 31) * 4;
  const float* qb = q    + (size_t)b * C_ * L_;
  const float* kb = kten + (size_t)b * C_ * L_;

  for (int k0 = 0; k0 < C_; k0 += 8) {
    float4 avv = *(const float4*)&qb[(size_t)(k0 + kk) * L_ + l0 + lq];
    float4 bvv = *(const float4*)&kb[(size_t)(k0 + kk) * L_ + m0 + lq];
    __syncthreads();
    *(float4*)&As[kk][lq] = avv;
    *(float4*)&Bs[kk][lq] = bvv;
    __syncthreads();
#pragma unroll
    for (int k2 = 0; k2 < 8; ++k2) {
      float4 a0 = *(const float4*)&As[k2][tm*4];
      float4 a1 = *(const float4*)&As[k2][tm*4+64];
      float4 b0 = *(const float4*)&Bs[k2][tn*4];
      float4 b1 = *(const float4*)&Bs[k2][tn*4+64];
      float a[8]  = {a0.x,a0.y,a0.z,a0.w,a1.x,a1.y,a1.z,a1.w};
      float bb[8] = {b0.x,b0.y,b0.z,b0.w,b1.x,b1.y,b1.z,b1.w};
#pragma unroll
      for (int i = 0; i < 8; ++i)
#pragma unroll
        for (int j = 0; j < 8; ++j)
          acc[i][j] += a[i] * bb[j];
    }
  }
  const float* pm = mask + (size_t)b * L_;
  float lm[8];
#pragma unroll
  for (int j = 0; j < 8; ++j) {
    int c = m0 + tn*4 + ((j < 4) ? j : (64 + j - 4));
    lm[j] = logf(pm[c] + 1e-6f);
  }
  float* ab = att + (size_t)bz * L_ * L_;
#pragma unroll
  for (int i = 0; i < 8; ++i) {
    int r = l0 + ((i < 4) ? (tm*4 + i) : (64 + tm*4 + (i - 4)));
    float4 v0 = make_float4(acc[i][0]*0.0625f+lm[0], acc[i][1]*0.0625f+lm[1],
                            acc[i][2]*0.0625f+lm[2], acc[i][3]*0.0625f+lm[3]);
    float4 v1 = make_float4(acc[i][4]*0.0625f+lm[4], acc[i][5]*0.0625f+lm[5],
                            acc[i][6]*0.0625f+lm[6], acc[i][7]*0.0625f+lm[7]);
    *(float4*)&ab[(size_t)r * L_ + m0 + tn*4]      = v0;
    *(float4*)&ab[(size_t)r * L_ + m0 + tn*4 + 64] = v1;
  }
}

// ---------------------------------------------------------------------------
// Kernel 3: row softmax over m (length 2048) + multiply by pm[m].
// One 256-thread block per row, 8 elements/thread.
// ---------------------------------------------------------------------------
__global__ __launch_bounds__(256) void softmax_kernel(
    float* __restrict__ att, const float* __restrict__ mask, int bbase)
{
  const int bz = blockIdx.y, b = bbase + bz;
  const int row = blockIdx.x;
  float* rp = att + ((size_t)bz * L_ + row) * L_;
  const float* pm = mask + (size_t)b * L_;
  const int tid = threadIdx.x;

  float4 v0 = *(const float4*)&rp[tid*8];
  float4 v1 = *(const float4*)&rp[tid*8+4];
  float x[8] = {v0.x,v0.y,v0.z,v0.w,v1.x,v1.y,v1.z,v1.w};

  float mx = x[0];
#pragma unroll
  for (int j = 1; j < 8; ++j) mx = fmaxf(mx, x[j]);
#pragma unroll
  for (int off = 32; off > 0; off >>= 1) mx = fmaxf(mx, __shfl_xor(mx, off));
  __shared__ float sm[4], ss[4];
  const int wid = tid >> 6, lane = tid & 63;
  if (lane == 0) sm[wid] = mx;
  __syncthreads();
  mx = fmaxf(fmaxf(sm[0], sm[1]), fmaxf(sm[2], sm[3]));

  float e[8]; float sum = 0.f;
#pragma unroll
  for (int j = 0; j < 8; ++j) { e[j] = __expf(x[j] - mx); sum += e[j]; }
#pragma unroll
  for (int off = 32; off > 0; off >>= 1) sum += __shfl_xor(sum, off);
  if (lane == 0) ss[wid] = sum;
  __syncthreads();
  sum = ss[0] + ss[1] + ss[2] + ss[3];
  float inv = 1.0f / sum;

  float4 p0 = *(const float4*)&pm[tid*8];
  float4 p1 = *(const float4*)&pm[tid*8+4];
  float pp[8] = {p0.x,p0.y,p0.z,p0.w,p1.x,p1.y,p1.z,p1.w};
#pragma unroll
  for (int j = 0; j < 8; ++j) x[j] = e[j] * inv * pp[j];
  *(float4*)&rp[tid*8]   = make_float4(x[0],x[1],x[2],x[3]);
  *(float4*)&rp[tid*8+4] = make_float4(x[4],x[5],x[6],x[7]);
}

// ---------------------------------------------------------------------------
// Kernel 4: h[c,l] = sum_m v[c,m] * att[l,m].  Contraction over m (contiguous in
// both operands) -> both transpose-staged. BM=64 (c), BN=128 (l), 4x8 microtile.
// ---------------------------------------------------------------------------
__global__ __launch_bounds__(256) void pv_kernel(
    const float* __restrict__ vten, const float* __restrict__ att,
    float* __restrict__ h, int bbase)
{
  const int bz = blockIdx.z, b = bbase + bz;
  const int c0 = blockIdx.y * 64;
  const int l0 = blockIdx.x * 128;
  const int tid = threadIdx.x;
  const int tm = tid >> 4, tn = tid & 15;

  __shared__ float As[8][64];    // [m][c]
  __shared__ float Bs[8][128];   // [m][l]
  float acc[4][8] = {};

  const float* vb = vten + (size_t)b * C_ * L_;
  const float* ab = att  + (size_t)bz * L_ * L_;

  for (int k0 = 0; k0 < L_; k0 += 8) {
    float4 avv = make_float4(0,0,0,0);
    const int am = tid >> 1, akq = (tid & 1) * 4;
    if (tid < 128) avv = *(const float4*)&vb[(size_t)(c0 + am) * L_ + k0 + akq];
    const int bm = tid >> 1, bkq = (tid & 1) * 4;
    float4 bvv = *(const float4*)&ab[(size_t)(l0 + bm) * L_ + k0 + bkq];
    __syncthreads();
    if (tid < 128) {
      As[akq+0][am] = avv.x; As[akq+1][am] = avv.y; As[akq+2][am] = avv.z; As[akq+3][am] = avv.w;
    }
    Bs[bkq+0][bm] = bvv.x; Bs[bkq+1][bm] = bvv.y; Bs[bkq+2][bm] = bvv.z; Bs[bkq+3][bm] = bvv.w;
    __syncthreads();
#pragma unroll
    for (int kk = 0; kk < 8; ++kk) {
      float4 a0 = *(const float4*)&As[kk][tm*4];
      float4 b0 = *(const float4*)&Bs[kk][tn*4];
      float4 b1 = *(const float4*)&Bs[kk][tn*4+64];
      float a[4]  = {a0.x,a0.y,a0.z,a0.w};
      float bb[8] = {b0.x,b0.y,b0.z,b0.w,b1.x,b1.y,b1.z,b1.w};
#pragma unroll
      for (int i = 0; i < 4; ++i)
#pragma unroll
        for (int j = 0; j < 8; ++j)
          acc[i][j] += a[i] * bb[j];
    }
  }
#pragma unroll
  for (int i = 0; i < 4; ++i) {
    int r = c0 + tm*4 + i;
    float4 o0 = make_float4(acc[i][0],acc[i][1],acc[i][2],acc[i][3]);
    float4 o1 = make_float4(acc[i][4],acc[i][5],acc[i][6],acc[i][7]);
    *(float4*)&h[((size_t)b * C_ + r) * L_ + l0 + tn*4]      = o0;
    *(float4*)&h[((size_t)b * C_ + r) * L_ + l0 + tn*4 + 64] = o1;
  }
}

// ---------------------------------------------------------------------------
// Kernel 5: out[d,l] = (sum_c Wo[d,c]*relu(h[c,l]) + bo[d]) * mask[l]
// ---------------------------------------------------------------------------
__global__ __launch_bounds__(256) void proj_kernel(
    const float* __restrict__ h, const float* __restrict__ Wo,
    const float* __restrict__ bo, const float* __restrict__ mask,
    float* __restrict__ out)
{
  const int b = blockIdx.z;
  const int m0 = blockIdx.y * 128;
  const int n0 = blockIdx.x * 128;
  const int tid = threadIdx.x;
  const int tm = tid >> 4, tn = tid & 15;

  __shared__ float As[8][128];
  __shared__ float Bs[8][128];
  float acc[8][8] = {};

  const int am = tid >> 1, ak = (tid & 1) * 4;
  const int kk = tid >> 5, lq = (tid & 31) * 4;
  const float* hb = h + (size_t)b * C_ * L_;

  for (int k0 = 0; k0 < C_; k0 += 8) {
    float4 avv = *(const float4*)&Wo[(size_t)(m0 + am) * C_ + k0 + ak];
    float4 bvv = *(const float4*)&hb[(size_t)(k0 + kk) * L_ + n0 + lq];
    bvv.x = fmaxf(bvv.x, 0.f); bvv.y = fmaxf(bvv.y, 0.f);
    bvv.z = fmaxf(bvv.z, 0.f); bvv.w = fmaxf(bvv.w, 0.f);
    __syncthreads();
    As[ak+0][am] = avv.x; As[ak+1][am] = avv.y; As[ak+2][am] = avv.z; As[ak+3][am] = avv.w;
    *(float4*)&Bs[kk][lq] = bvv;
    __syncthreads();
#pragma unroll
    for (int k2 = 0; k2 < 8; ++k2) {
      float4 a0 = *(const float4*)&As[k2][tm*4];
      float4 a1 = *(const float4*)&As[k2][tm*4+64];
      float4 b0 = *(const float4*)&Bs[k2][tn*4];
      float4 b1 = *(const float4*)&Bs[k2][tn*4+64];
      float a[8]  = {a0.x,a0.y,a0.z,a0.w,a1.x,a1.y,a1.z,a1.w};
      float bb[8] = {b0.x,b0.y,b0.z,b0.w,b1.x,b1.y,b1.z,b1.w};
#pragma unroll
      for (int i = 0; i < 8; ++i)
#pragma unroll
        for (int j = 0; j < 8; ++j)
          acc[i][j] += a[i] * bb[j];
    }
  }
  const float* pmb = mask + (size_t)b * L_;
#pragma unroll
  for (int i = 0; i < 8; ++i) {
    int r = m0 + ((i < 4) ? (tm*4 + i) : (64 + tm*4 + (i - 4)));
    float bs = bo[r];
    float mc[8];
#pragma unroll
    for (int j = 0; j < 8; ++j) {
      int c = n0 + tn*4 + ((j < 4) ? j : (64 + j - 4));
      mc[j] = pmb[c];
    }
    float4 v0 = make_float4((acc[i][0]+bs)*mc[0], (acc[i][1]+bs)*mc[1],
                            (acc[i][2]+bs)*mc[2], (acc[i][3]+bs)*mc[3]);
    float4 v1 = make_float4((acc[i][4]+bs)*mc[4], (acc[i][5]+bs)*mc[5],
                            (acc[i][6]+bs)*mc[6], (acc[i][7]+bs)*mc[7]);
    *(float4*)&out[((size_t)b * D_ + r) * L_ + n0 + tn*4]      = v0;
    *(float4*)&out[((size_t)b * D_ + r) * L_ + n0 + tn*4 + 64] = v1;
  }
}

// ---------------------------------------------------------------------------
extern "C" void kernel_launch(void* const* d_in, const int* in_sizes, int n_in,
                              void* d_out, int out_size, void* d_ws, size_t ws_size,
                              hipStream_t stream) {
  (void)in_sizes; (void)n_in; (void)out_size;
  const float* x1   = (const float*)d_in[0];
  // d_in[1] = x2 : unused by the reference
  const float* mask = (const float*)d_in[2];
  const float* Wq   = (const float*)d_in[3];
  const float* bq   = (const float*)d_in[4];
  const float* Wk   = (const float*)d_in[5];
  const float* bk   = (const float*)d_in[6];
  const float* Wv   = (const float*)d_in[7];
  const float* bv   = (const float*)d_in[8];
  const float* Wo   = (const float*)d_in[9];
  const float* bo   = (const float*)d_in[10];
  float* out = (float*)d_out;
  float* ws  = (float*)d_ws;

  const size_t BCLs = (size_t)B_ * C_ * L_;           // 4,194,304 elements
  float* q    = ws;
  float* kten = ws + BCLs;
  float* vten = ws + 2 * BCLs;
  float* att  = ws + 3 * BCLs;
  float* h    = q;  // q is dead once all S-tiles are computed; reuse its buffer

  const size_t fullNeed = (3 * BCLs + (size_t)B_ * L_ * L_) * sizeof(float); // ~185 MB
  const bool full = ws_size >= fullNeed;

  qkv_kernel<<<dim3(L_/128, C_/128, 3*B_), 256, 0, stream>>>(
      x1, Wq, bq, Wk, bk, Wv, bv, q, kten, vten);

  if (full) {
    s_kernel      <<<dim3(L_/128, L_/128, B_), 256, 0, stream>>>(q, kten, mask, att, 0);
    softmax_kernel<<<dim3(L_, B_),             256, 0, stream>>>(att, mask, 0);
    pv_kernel     <<<dim3(L_/128, C_/64, B_),  256, 0, stream>>>(vten, att, h, 0);
  } else {
    for (int b = 0; b < B_; ++b) {
      s_kernel      <<<dim3(L_/128, L_/128, 1), 256, 0, stream>>>(q, kten, mask, att, b);
      softmax_kernel<<<dim3(L_, 1),             256, 0, stream>>>(att, mask, b);
      pv_kernel     <<<dim3(L_/128, C_/64, 1),  256, 0, stream>>>(vten, att, h, b);
    }
  }

  proj_kernel<<<dim3(L_/128, D_/128, B_), 256, 0, stream>>>(h, Wo, bo, mask, out);
}

// Round 2
// 415.654 us; speedup vs baseline: 1.8945x; 1.8945x over previous
//
#include <hip/hip_runtime.h>
#include <hip/hip_bf16.h>
#include <cstdint>
#include <cstddef>

#define B_ 8
#define D_ 512
#define L_ 2048
#define C_ 256

typedef short short8 __attribute__((ext_vector_type(8)));
typedef float floatx4 __attribute__((ext_vector_type(4)));

__device__ __forceinline__ ushort bf16_of(float x) {
  union { float f; uint32_t u; } v; v.f = x;
  uint32_t r = v.u + 0x7fff + ((v.u >> 16) & 1);   // round-to-nearest-even
  return (ushort)(r >> 16);
}
__device__ __forceinline__ float f32_of(ushort h) {
  union { uint32_t u; float f; } v; v.u = ((uint32_t)h) << 16; return v.f;
}
__device__ __forceinline__ void split2(float x, ushort& h, ushort& l) {
  h = bf16_of(x);
  l = bf16_of(x - f32_of(h));
}

// ---------------------------------------------------------------------------
// Generic split-bf16 MFMA GEMM: D[m,n] = sum_k A[m,k]*B[n,k]  (both k-contig)
// 128x128 tile, 4 waves (2x2 of 64x64), 16x16x32 bf16 MFMA, 3-pass split.
// EPI: 0 split-out + bias[col]   (qT,kT)
//      1 split-out + bias[row]   (v)
//      2 f32 out: acc*scale + logf(aux1[col]+1e-6)   (S)
//      3 f32 atomicAdd            (pv fallback)
//      4 f32 out: (acc+aux1[row])*aux2[col]          (final proj)
//      5 f32 plain store (split-K partial)           (pv full)
// ---------------------------------------------------------------------------
template<int EPI>
__global__ __launch_bounds__(256) void mm_kernel(
    const ushort* __restrict__ Ah, const ushort* __restrict__ Al, long sA, int lda,
    const ushort* __restrict__ Bh, const ushort* __restrict__ Bl, long sB, int ldb,
    int K, int nsplit, long sKpart,
    ushort* __restrict__ o1, ushort* __restrict__ o2, float* __restrict__ of,
    long sO, int ldo,
    const float* __restrict__ aux1, long saux1,
    const float* __restrict__ aux2, long saux2, float scale)
{
  const int z = blockIdx.z;
  const int b = z / nsplit, ks = z % nsplit;
  Ah += (long)b * sA + (long)ks * K;
  Al += (long)b * sA + (long)ks * K;
  Bh += (long)b * sB + (long)ks * K;
  Bl += (long)b * sB + (long)ks * K;
  const int m0 = blockIdx.y * 128, n0 = blockIdx.x * 128;

  // padded stride 40 halves (80 B): rows 0..7 cover all 32 banks; 16 rows -> 2-way (free)
  __shared__ ushort Ash[128][40], Asl[128][40], Bsh[128][40], Bsl[128][40];

  const int tid = threadIdx.x;
  const int wv = tid >> 6, lane = tid & 63;
  const int wm = (wv >> 1) * 64, wn = (wv & 1) * 64;
  const int lr = lane & 15, lg = lane >> 4;

  floatx4 acc[4][4] = {};

  const int srow = tid >> 1;       // 0..127
  const int sc   = (tid & 1) * 8;  // 0 or 8 (halves); chunks sc and sc+16 cover k 0..31

  for (int k0 = 0; k0 < K; k0 += 32) {
    const ushort* pAh = Ah + (size_t)(m0 + srow) * lda + k0;
    const ushort* pAl = Al + (size_t)(m0 + srow) * lda + k0;
    const ushort* pBh = Bh + (size_t)(n0 + srow) * ldb + k0;
    const ushort* pBl = Bl + (size_t)(n0 + srow) * ldb + k0;
    short8 a0 = *(const short8*)(pAh + sc);
    short8 a1 = *(const short8*)(pAh + sc + 16);
    short8 a2 = *(const short8*)(pAl + sc);
    short8 a3 = *(const short8*)(pAl + sc + 16);
    short8 b0 = *(const short8*)(pBh + sc);
    short8 b1 = *(const short8*)(pBh + sc + 16);
    short8 b2 = *(const short8*)(pBl + sc);
    short8 b3 = *(const short8*)(pBl + sc + 16);
    __syncthreads();
    *(short8*)&Ash[srow][sc]      = a0;
    *(short8*)&Ash[srow][sc + 16] = a1;
    *(short8*)&Asl[srow][sc]      = a2;
    *(short8*)&Asl[srow][sc + 16] = a3;
    *(short8*)&Bsh[srow][sc]      = b0;
    *(short8*)&Bsh[srow][sc + 16] = b1;
    *(short8*)&Bsl[srow][sc]      = b2;
    *(short8*)&Bsl[srow][sc + 16] = b3;
    __syncthreads();

    short8 fah[4], fal[4], fbh[4], fbl[4];
#pragma unroll
    for (int i = 0; i < 4; ++i) {
      fah[i] = *(const short8*)&Ash[wm + i*16 + lr][lg*8];
      fal[i] = *(const short8*)&Asl[wm + i*16 + lr][lg*8];
      fbh[i] = *(const short8*)&Bsh[wn + i*16 + lr][lg*8];
      fbl[i] = *(const short8*)&Bsl[wn + i*16 + lr][lg*8];
    }
#pragma unroll
    for (int i = 0; i < 4; ++i)
#pragma unroll
      for (int j = 0; j < 4; ++j) {
        acc[i][j] = __builtin_amdgcn_mfma_f32_16x16x32_bf16(fah[i], fbh[j], acc[i][j], 0, 0, 0);
        acc[i][j] = __builtin_amdgcn_mfma_f32_16x16x32_bf16(fah[i], fbl[j], acc[i][j], 0, 0, 0);
        acc[i][j] = __builtin_amdgcn_mfma_f32_16x16x32_bf16(fal[i], fbh[j], acc[i][j], 0, 0, 0);
      }
  }

  const long ooff = (long)b * sO + (long)ks * sKpart;
  float lm[4];
  if constexpr (EPI == 2) {
#pragma unroll
    for (int j = 0; j < 4; ++j)
      lm[j] = logf(aux1[(long)b * saux1 + n0 + wn + j*16 + lr] + 1e-6f);
  }
#pragma unroll
  for (int i = 0; i < 4; ++i) {
#pragma unroll
    for (int j = 0; j < 4; ++j) {
#pragma unroll
      for (int r = 0; r < 4; ++r) {
        const int row = m0 + wm + i*16 + lg*4 + r;   // C/D: row=(lane>>4)*4+reg
        const int col = n0 + wn + j*16 + lr;         //       col=lane&15
        float v = acc[i][j][r];
        const long oidx = ooff + (long)row * ldo + col;
        if constexpr (EPI == 0) {
          v += aux1[(long)b * saux1 + col];
          ushort h, l; split2(v, h, l); o1[oidx] = h; o2[oidx] = l;
        } else if constexpr (EPI == 1) {
          v += aux1[(long)b * saux1 + row];
          ushort h, l; split2(v, h, l); o1[oidx] = h; o2[oidx] = l;
        } else if constexpr (EPI == 2) {
          of[oidx] = v * scale + lm[j];
        } else if constexpr (EPI == 3) {
          atomicAdd(&of[oidx], v);
        } else if constexpr (EPI == 4) {
          of[oidx] = (v + aux1[(long)b * saux1 + row]) * aux2[(long)b * saux2 + col];
        } else {
          of[oidx] = v;
        }
      }
    }
  }
}

// ---------------------------------------------------------------------------
// x1 (B,D,L) f32  ->  x1T (B,L,D) split bf16 pair. 32x32 tiles.
// ---------------------------------------------------------------------------
__global__ __launch_bounds__(256) void transpose_split_kernel(
    const float* __restrict__ x1, ushort* __restrict__ th, ushort* __restrict__ tl)
{
  __shared__ float t[32][33];
  const int b = blockIdx.z;
  const int l0 = blockIdx.x * 32, d0 = blockIdx.y * 32;
  const int tid = threadIdx.x;
  const int dr = tid >> 3, l4 = (tid & 7) * 4;
  float4 v = *(const float4*)(x1 + ((size_t)b * D_ + d0 + dr) * L_ + l0 + l4);
  t[dr][l4+0] = v.x; t[dr][l4+1] = v.y; t[dr][l4+2] = v.z; t[dr][l4+3] = v.w;
  __syncthreads();
  const int lr = tid >> 3, d4 = (tid & 7) * 4;
  ushort hh[4], ll[4];
#pragma unroll
  for (int j = 0; j < 4; ++j) split2(t[d4+j][lr], hh[j], ll[j]);
  const size_t o = ((size_t)b * L_ + l0 + lr) * D_ + d0 + d4;
  *(ushort4*)&th[o] = make_ushort4(hh[0], hh[1], hh[2], hh[3]);
  *(ushort4*)&tl[o] = make_ushort4(ll[0], ll[1], ll[2], ll[3]);
}

// ---------------------------------------------------------------------------
// Split the 4 weight matrices (each 131072 f32) into bf16 hi/lo pairs.
// wbase layout: [Wqh][Wql][Wkh][Wkl][Wvh][Wvl][Woh][Wol], each 131072 ushorts.
// ---------------------------------------------------------------------------
__global__ __launch_bounds__(256) void splitw_kernel(
    const float* __restrict__ w0, const float* __restrict__ w1,
    const float* __restrict__ w2, const float* __restrict__ w3,
    ushort* __restrict__ wbase)
{
  const int z = blockIdx.z;
  const float* s = (z == 0) ? w0 : (z == 1) ? w1 : (z == 2) ? w2 : w3;
  ushort* dh = wbase + (size_t)z * 262144;
  ushort* dl = dh + 131072;
  const int i = (blockIdx.x * 256 + threadIdx.x) * 4;
  float4 v = *(const float4*)(s + i);
  ushort h[4], l[4];
  split2(v.x, h[0], l[0]); split2(v.y, h[1], l[1]);
  split2(v.z, h[2], l[2]); split2(v.w, h[3], l[3]);
  *(ushort4*)&dh[i] = make_ushort4(h[0], h[1], h[2], h[3]);
  *(ushort4*)&dl[i] = make_ushort4(l[0], l[1], l[2], l[3]);
}

// ---------------------------------------------------------------------------
// Row softmax over m + *pm[m]; writes split bf16 hi/lo IN PLACE into att row
// bytes: hi at ushort[0..2047], lo at ushort[2048..4095].
// ---------------------------------------------------------------------------
__global__ __launch_bounds__(256) void softmax_split_kernel(
    float* __restrict__ att, const float* __restrict__ mask, int bbase)
{
  const int bz = blockIdx.y;
  const int row = blockIdx.x;
  float* rp = att + ((size_t)bz * L_ + row) * L_;
  const float* pm = mask + (size_t)(bbase + bz) * L_;
  const int tid = threadIdx.x;

  float4 v0 = *(const float4*)&rp[tid*8];
  float4 v1 = *(const float4*)&rp[tid*8 + 4];
  float x[8] = {v0.x, v0.y, v0.z, v0.w, v1.x, v1.y, v1.z, v1.w};

  float mx = x[0];
#pragma unroll
  for (int j = 1; j < 8; ++j) mx = fmaxf(mx, x[j]);
#pragma unroll
  for (int off = 32; off > 0; off >>= 1) mx = fmaxf(mx, __shfl_xor(mx, off));
  __shared__ float sm[4], ss[4];
  const int wid = tid >> 6, lane = tid & 63;
  if (lane == 0) sm[wid] = mx;
  __syncthreads();
  mx = fmaxf(fmaxf(sm[0], sm[1]), fmaxf(sm[2], sm[3]));

  float e[8]; float sum = 0.f;
#pragma unroll
  for (int j = 0; j < 8; ++j) { e[j] = __expf(x[j] - mx); sum += e[j]; }
#pragma unroll
  for (int off = 32; off > 0; off >>= 1) sum += __shfl_xor(sum, off);
  if (lane == 0) ss[wid] = sum;
  __syncthreads();
  sum = ss[0] + ss[1] + ss[2] + ss[3];
  const float inv = 1.0f / sum;

  float4 p0 = *(const float4*)&pm[tid*8];
  float4 p1 = *(const float4*)&pm[tid*8 + 4];
  float pp[8] = {p0.x, p0.y, p0.z, p0.w, p1.x, p1.y, p1.z, p1.w};

  short8 hi8, lo8;
#pragma unroll
  for (int j = 0; j < 8; ++j) {
    float p = e[j] * inv * pp[j];
    ushort h, l; split2(p, h, l);
    hi8[j] = (short)h; lo8[j] = (short)l;
  }
  ushort* rh = (ushort*)rp;
  *(short8*)&rh[tid*8]        = hi8;   // all reads of rp happened before the syncs above
  *(short8*)&rh[L_ + tid*8]   = lo8;
}

// ---------------------------------------------------------------------------
// hT = sum of nparts partials (stride n), relu, split bf16. n = B*L*C.
// ---------------------------------------------------------------------------
__global__ __launch_bounds__(256) void reduce_relu_split_kernel(
    const float* __restrict__ p, int nparts, int n,
    ushort* __restrict__ oh, ushort* __restrict__ ol)
{
  const int i = (blockIdx.x * 256 + threadIdx.x) * 4;
  if (i >= n) return;
  float4 s = *(const float4*)&p[i];
  for (int q = 1; q < nparts; ++q) {
    float4 t = *(const float4*)&p[(size_t)q * n + i];
    s.x += t.x; s.y += t.y; s.z += t.z; s.w += t.w;
  }
  float vv[4] = {fmaxf(s.x, 0.f), fmaxf(s.y, 0.f), fmaxf(s.z, 0.f), fmaxf(s.w, 0.f)};
  ushort h[4], l[4];
#pragma unroll
  for (int j = 0; j < 4; ++j) split2(vv[j], h[j], l[j]);
  *(ushort4*)&oh[i] = make_ushort4(h[0], h[1], h[2], h[3]);
  *(ushort4*)&ol[i] = make_ushort4(l[0], l[1], l[2], l[3]);
}

// ---------------------------------------------------------------------------
extern "C" void kernel_launch(void* const* d_in, const int* in_sizes, int n_in,
                              void* d_out, int out_size, void* d_ws, size_t ws_size,
                              hipStream_t stream) {
  (void)in_sizes; (void)n_in; (void)out_size;
  const float* x1   = (const float*)d_in[0];
  const float* mask = (const float*)d_in[2];
  const float* Wq   = (const float*)d_in[3];
  const float* bq   = (const float*)d_in[4];
  const float* Wk   = (const float*)d_in[5];
  const float* bk   = (const float*)d_in[6];
  const float* Wv   = (const float*)d_in[7];
  const float* bv   = (const float*)d_in[8];
  const float* Wo   = (const float*)d_in[9];
  const float* bo   = (const float*)d_in[10];
  float* out = (float*)d_out;
  uint8_t* w8 = (uint8_t*)d_ws;

  // ws layout (bytes)
  const size_t oX1Th = 0;         // 16777216
  const size_t oX1Tl = 16777216;
  const size_t oQTh  = 33554432;  // 8388608 each
  const size_t oQTl  = 41943040;
  const size_t oKTh  = 50331648;
  const size_t oKTl  = 58720256;
  const size_t oW    = 67108864;  // 8 x 262144
  const size_t oVh   = 69206016;
  const size_t oVl   = 77594624;
  const size_t oATT  = 85983232;  // full: 134217728 ; fallback: 33554432

  ushort* x1Th = (ushort*)(w8 + oX1Th);
  ushort* x1Tl = (ushort*)(w8 + oX1Tl);
  ushort* qTh  = (ushort*)(w8 + oQTh);
  ushort* qTl  = (ushort*)(w8 + oQTl);
  ushort* kTh  = (ushort*)(w8 + oKTh);
  ushort* kTl  = (ushort*)(w8 + oKTl);
  ushort* wb   = (ushort*)(w8 + oW);
  ushort* Wqh = wb;             ushort* Wql = wb + 131072;
  ushort* Wkh = wb + 262144;    ushort* Wkl = wb + 393216;
  ushort* Wvh = wb + 524288;    ushort* Wvl = wb + 655360;
  ushort* Woh = wb + 786432;    ushort* Wol = wb + 917504;
  ushort* vh   = (ushort*)(w8 + oVh);
  ushort* vl   = (ushort*)(w8 + oVl);
  float*  att  = (float*)(w8 + oATT);

  const bool full = ws_size >= 220200960ULL;

  // 1) x1 -> x1T split
  transpose_split_kernel<<<dim3(L_/32, D_/32, B_), 256, 0, stream>>>(x1, x1Th, x1Tl);
  // 2) weights split
  splitw_kernel<<<dim3(128, 1, 4), 256, 0, stream>>>(Wq, Wk, Wv, Wo, wb);
  // 3) qT = x1T * Wq^T + bq[col]   (L x C, split out)
  mm_kernel<0><<<dim3(C_/128, L_/128, B_), 256, 0, stream>>>(
      x1Th, x1Tl, (long)L_*D_, D_, Wqh, Wql, 0, D_, D_, 1, 0,
      qTh, qTl, nullptr, (long)L_*C_, C_, bq, 0, nullptr, 0, 0.f);
  // 4) kT
  mm_kernel<0><<<dim3(C_/128, L_/128, B_), 256, 0, stream>>>(
      x1Th, x1Tl, (long)L_*D_, D_, Wkh, Wkl, 0, D_, D_, 1, 0,
      kTh, kTl, nullptr, (long)L_*C_, C_, bk, 0, nullptr, 0, 0.f);
  // 5) v = Wv * x1 + bv[row]       (C x L, split out)
  mm_kernel<1><<<dim3(L_/128, C_/128, B_), 256, 0, stream>>>(
      Wvh, Wvl, 0, D_, x1Th, x1Tl, (long)L_*D_, D_, D_, 1, 0,
      vh, vl, nullptr, (long)C_*L_, L_, bv, 0, nullptr, 0, 0.f);

  if (full) {
    float* part = (float*)w8;                       // 4 x B*L*C f32 over dead x1T+qk
    ushort* hTh = (ushort*)(w8 + oATT);             // over dead att after pv
    ushort* hTl = (ushort*)(w8 + oATT + 8388608);
    // 6) S = qT*kT^T /16 + log(mask+1e-6)
    mm_kernel<2><<<dim3(L_/128, L_/128, B_), 256, 0, stream>>>(
        qTh, qTl, (long)L_*C_, C_, kTh, kTl, (long)L_*C_, C_, C_, 1, 0,
        nullptr, nullptr, att, (long)L_*L_, L_, mask, L_, nullptr, 0, 0.0625f);
    // 7) softmax + *pm, split in place
    softmax_split_kernel<<<dim3(L_, B_), 256, 0, stream>>>(att, mask, 0);
    // 8) pv split-K=4 partials:  hT[l,c] = sum_m att[l,m] * v[c,m]
    mm_kernel<5><<<dim3(C_/128, L_/128, B_*4), 256, 0, stream>>>(
        (ushort*)att, (ushort*)att + L_, (long)L_*L_*2, 2*L_,
        vh, vl, (long)C_*L_, L_, 512, 4, (long)B_*L_*C_,
        nullptr, nullptr, part, (long)L_*C_, C_, nullptr, 0, nullptr, 0, 0.f);
    // 9) reduce + relu + split
    reduce_relu_split_kernel<<<dim3(B_*L_*C_/1024), 256, 0, stream>>>(
        part, 4, B_*L_*C_, hTh, hTl);
    // 10) out = (Wo*relu(h) + bo[row]) * mask[col]
    mm_kernel<4><<<dim3(L_/128, D_/128, B_), 256, 0, stream>>>(
        Woh, Wol, 0, C_, hTh, hTl, (long)L_*C_, C_, C_, 1, 0,
        nullptr, nullptr, out, (long)D_*L_, L_, bo, 0, mask, L_, 0.f);
  } else {
    float*  hT32 = (float*)w8;                      // over dead x1T
    ushort* hTh  = (ushort*)(w8 + 16777216);
    ushort* hTl  = (ushort*)(w8 + 25165824);
    hipMemsetAsync(hT32, 0, 16777216, stream);
    for (int g = 0; g < 4; ++g) {
      mm_kernel<2><<<dim3(L_/128, L_/128, 2), 256, 0, stream>>>(
          qTh + (size_t)g*2*L_*C_, qTl + (size_t)g*2*L_*C_, (long)L_*C_, C_,
          kTh + (size_t)g*2*L_*C_, kTl + (size_t)g*2*L_*C_, (long)L_*C_, C_, C_, 1, 0,
          nullptr, nullptr, att, (long)L_*L_, L_, mask + (size_t)g*2*L_, L_, nullptr, 0, 0.0625f);
      softmax_split_kernel<<<dim3(L_, 2), 256, 0, stream>>>(att, mask, g*2);
      mm_kernel<3><<<dim3(C_/128, L_/128, 2*4), 256, 0, stream>>>(
          (ushort*)att, (ushort*)att + L_, (long)L_*L_*2, 2*L_,
          vh + (size_t)g*2*C_*L_, vl + (size_t)g*2*C_*L_, (long)C_*L_, L_, 512, 4, 0,
          nullptr, nullptr, hT32 + (size_t)g*2*L_*C_, (long)L_*C_, C_, nullptr, 0, nullptr, 0, 0.f);
    }
    reduce_relu_split_kernel<<<dim3(B_*L_*C_/1024), 256, 0, stream>>>(
        hT32, 1, B_*L_*C_, hTh, hTl);
    mm_kernel<4><<<dim3(L_/128, D_/128, B_), 256, 0, stream>>>(
        Woh, Wol, 0, C_, hTh, hTl, (long)L_*C_, C_, C_, 1, 0,
        nullptr, nullptr, out, (long)D_*L_, L_, bo, 0, mask, L_, 0.f);
  }
}

// Round 3
// 395.935 us; speedup vs baseline: 1.9888x; 1.0498x over previous
//
#include <hip/hip_runtime.h>
#include <hip/hip_bf16.h>
#include <cstdint>
#include <cstddef>

#define B_ 8
#define D_ 512
#define L_ 2048
#define C_ 256

typedef short short8 __attribute__((ext_vector_type(8)));
typedef float floatx4 __attribute__((ext_vector_type(4)));

#define MFMA16 __builtin_amdgcn_mfma_f32_16x16x32_bf16

__device__ __forceinline__ ushort bf16_of(float x) {
  union { float f; uint32_t u; } v; v.f = x;
  uint32_t r = v.u + 0x7fff + ((v.u >> 16) & 1);   // RNE
  return (ushort)(r >> 16);
}
__device__ __forceinline__ float f32_of(ushort h) {
  union { uint32_t u; float f; } v; v.u = ((uint32_t)h) << 16; return v.f;
}
__device__ __forceinline__ void split2(float x, ushort& h, ushort& l) {
  h = bf16_of(x);
  l = bf16_of(x - f32_of(h));
}

// ---------------------------------------------------------------------------
// Split-bf16 MFMA GEMM: D[m,n] = sum_k A[m,k]*B[n,k] (both k-contig)
// EPI 0: split-out, v=(acc+bias[col])*scale    (qT with scale=1/16, kT)
// EPI 1: split-out, v= acc+bias[row]           (v)
// EPI 4: f32 out, v=(acc+aux1[row])*aux2[col]  (final proj)
// ---------------------------------------------------------------------------
template<int EPI>
__global__ __launch_bounds__(256) void mm_kernel(
    const ushort* __restrict__ Ah, const ushort* __restrict__ Al, long sA, int lda,
    const ushort* __restrict__ Bh, const ushort* __restrict__ Bl, long sB, int ldb,
    int K,
    ushort* __restrict__ o1, ushort* __restrict__ o2, float* __restrict__ of,
    long sO, int ldo,
    const float* __restrict__ aux1, long saux1,
    const float* __restrict__ aux2, long saux2, float scale)
{
  const int b = blockIdx.z;
  Ah += (long)b * sA;  Al += (long)b * sA;
  Bh += (long)b * sB;  Bl += (long)b * sB;
  const int m0 = blockIdx.y * 128, n0 = blockIdx.x * 128;

  __shared__ ushort Ash[128][40], Asl[128][40], Bsh[128][40], Bsl[128][40];

  const int tid = threadIdx.x;
  const int wv = tid >> 6, lane = tid & 63;
  const int wm = (wv >> 1) * 64, wn = (wv & 1) * 64;
  const int lr = lane & 15, lg = lane >> 4;

  floatx4 acc[4][4] = {};

  const int srow = tid >> 1;
  const int sc   = (tid & 1) * 8;

  for (int k0 = 0; k0 < K; k0 += 32) {
    const ushort* pAh = Ah + (size_t)(m0 + srow) * lda + k0;
    const ushort* pAl = Al + (size_t)(m0 + srow) * lda + k0;
    const ushort* pBh = Bh + (size_t)(n0 + srow) * ldb + k0;
    const ushort* pBl = Bl + (size_t)(n0 + srow) * ldb + k0;
    short8 a0 = *(const short8*)(pAh + sc);
    short8 a1 = *(const short8*)(pAh + sc + 16);
    short8 a2 = *(const short8*)(pAl + sc);
    short8 a3 = *(const short8*)(pAl + sc + 16);
    short8 b0 = *(const short8*)(pBh + sc);
    short8 b1 = *(const short8*)(pBh + sc + 16);
    short8 b2 = *(const short8*)(pBl + sc);
    short8 b3 = *(const short8*)(pBl + sc + 16);
    __syncthreads();
    *(short8*)&Ash[srow][sc]      = a0;
    *(short8*)&Ash[srow][sc + 16] = a1;
    *(short8*)&Asl[srow][sc]      = a2;
    *(short8*)&Asl[srow][sc + 16] = a3;
    *(short8*)&Bsh[srow][sc]      = b0;
    *(short8*)&Bsh[srow][sc + 16] = b1;
    *(short8*)&Bsl[srow][sc]      = b2;
    *(short8*)&Bsl[srow][sc + 16] = b3;
    __syncthreads();

    short8 fah[4], fal[4], fbh[4], fbl[4];
#pragma unroll
    for (int i = 0; i < 4; ++i) {
      fah[i] = *(const short8*)&Ash[wm + i*16 + lr][lg*8];
      fal[i] = *(const short8*)&Asl[wm + i*16 + lr][lg*8];
      fbh[i] = *(const short8*)&Bsh[wn + i*16 + lr][lg*8];
      fbl[i] = *(const short8*)&Bsl[wn + i*16 + lr][lg*8];
    }
#pragma unroll
    for (int i = 0; i < 4; ++i)
#pragma unroll
      for (int j = 0; j < 4; ++j) {
        acc[i][j] = MFMA16(fah[i], fbh[j], acc[i][j], 0, 0, 0);
        acc[i][j] = MFMA16(fah[i], fbl[j], acc[i][j], 0, 0, 0);
        acc[i][j] = MFMA16(fal[i], fbh[j], acc[i][j], 0, 0, 0);
      }
  }

  const long ooff = (long)b * sO;
#pragma unroll
  for (int i = 0; i < 4; ++i) {
#pragma unroll
    for (int j = 0; j < 4; ++j) {
#pragma unroll
      for (int r = 0; r < 4; ++r) {
        const int row = m0 + wm + i*16 + lg*4 + r;
        const int col = n0 + wn + j*16 + lr;
        float v = acc[i][j][r];
        const long oidx = ooff + (long)row * ldo + col;
        if constexpr (EPI == 0) {
          v = (v + aux1[(long)b * saux1 + col]) * scale;
          ushort h, l; split2(v, h, l); o1[oidx] = h; o2[oidx] = l;
        } else if constexpr (EPI == 1) {
          v += aux1[(long)b * saux1 + row];
          ushort h, l; split2(v, h, l); o1[oidx] = h; o2[oidx] = l;
        } else {
          of[oidx] = (v + aux1[(long)b * saux1 + row]) * aux2[(long)b * saux2 + col];
        }
      }
    }
  }
}

// ---------------------------------------------------------------------------
// x1 (B,D,L) f32 -> x1T (B,L,D) split bf16.
// ---------------------------------------------------------------------------
__global__ __launch_bounds__(256) void transpose_split_kernel(
    const float* __restrict__ x1, ushort* __restrict__ th, ushort* __restrict__ tl)
{
  __shared__ float t[32][33];
  const int b = blockIdx.z;
  const int l0 = blockIdx.x * 32, d0 = blockIdx.y * 32;
  const int tid = threadIdx.x;
  const int dr = tid >> 3, l4 = (tid & 7) * 4;
  float4 v = *(const float4*)(x1 + ((size_t)b * D_ + d0 + dr) * L_ + l0 + l4);
  t[dr][l4+0] = v.x; t[dr][l4+1] = v.y; t[dr][l4+2] = v.z; t[dr][l4+3] = v.w;
  __syncthreads();
  const int lr = tid >> 3, d4 = (tid & 7) * 4;
  ushort hh[4], ll[4];
#pragma unroll
  for (int j = 0; j < 4; ++j) split2(t[d4+j][lr], hh[j], ll[j]);
  const size_t o = ((size_t)b * L_ + l0 + lr) * D_ + d0 + d4;
  *(ushort4*)&th[o] = make_ushort4(hh[0], hh[1], hh[2], hh[3]);
  *(ushort4*)&tl[o] = make_ushort4(ll[0], ll[1], ll[2], ll[3]);
}

__global__ __launch_bounds__(256) void splitw_kernel(
    const float* __restrict__ w0, const float* __restrict__ w1,
    const float* __restrict__ w2, const float* __restrict__ w3,
    ushort* __restrict__ wbase)
{
  const int z = blockIdx.z;
  const float* s = (z == 0) ? w0 : (z == 1) ? w1 : (z == 2) ? w2 : w3;
  ushort* dh = wbase + (size_t)z * 262144;
  ushort* dl = dh + 131072;
  const int i = (blockIdx.x * 256 + threadIdx.x) * 4;
  float4 v = *(const float4*)(s + i);
  ushort h[4], l[4];
  split2(v.x, h[0], l[0]); split2(v.y, h[1], l[1]);
  split2(v.z, h[2], l[2]); split2(v.w, h[3], l[3]);
  *(ushort4*)&dh[i] = make_ushort4(h[0], h[1], h[2], h[3]);
  *(ushort4*)&dl[i] = make_ushort4(l[0], l[1], l[2], l[3]);
}

// ---------------------------------------------------------------------------
// Flash attention: S=qk^T(pre-scaled)+log(pm+1e-6), online softmax, O=P*pm*V.
// Block: 64 q-rows, 4 waves. kv-split 2 (blocks), KVBLK=32 time-shared LDS.
// Wave w: QK for q-rows 16w..16w+15 (Q in regs); PV for c-slice 64w..64w+63.
// Outputs UNNORMALIZED O partials + running (M, Sigma) per row per split.
// ---------------------------------------------------------------------------
__global__ __launch_bounds__(256, 2) void flash_kernel(
    const ushort* __restrict__ qTh, const ushort* __restrict__ qTl,
    const ushort* __restrict__ kTh, const ushort* __restrict__ kTl,
    const ushort* __restrict__ vh,  const ushort* __restrict__ vl,
    const float* __restrict__ mask,
    float* __restrict__ Opart, float* __restrict__ Mstat, float* __restrict__ Sstat)
{
  // union: K-tile [32][264] (8448) or V-tile [256][40] (10240), per split
  __shared__ __align__(16) ushort UNh[10240], UNl[10240];
  __shared__ __align__(16) ushort Ph[2560], Pl[2560];   // P [64][40]
  __shared__ float lmS[32], pmS[32], corS[64];
  __shared__ int flagS[4];

  const int f = blockIdx.x;
  const int b = f & 7, ks = (f >> 3) & 1, qt = f >> 4;
  const int q0 = qt * 64;
  const int tid = threadIdx.x;
  const int w = tid >> 6, lane = tid & 63;
  const int lr = lane & 15, g = lane >> 4;

  // Q fragments (B-operand): q-row = q0+16w+lr, k-chunks 0..7
  short8 qfh[8], qfl[8];
  {
    const size_t qoff = ((size_t)b * L_ + q0 + 16*w + lr) * C_ + g*8;
    const ushort* ph = qTh + qoff;
    const ushort* pl = qTl + qoff;
#pragma unroll
    for (int kc = 0; kc < 8; ++kc) {
      qfh[kc] = *(const short8*)(ph + kc*32);
      qfl[kc] = *(const short8*)(pl + kc*32);
    }
  }

  floatx4 O[4][4] = {};             // [row-frag][c-frag], c-slice = 64*w
  float M = -3.0e38f, Sp = 0.f;

  const int kvbase = ks * 1024;
  for (int step = 0; step < 32; ++step) {
    const int m0 = kvbase + step * 32;

    // ---- stage K-tile [32][264] + mask tiles ----
    {
      const int r = tid >> 3, seg = (tid & 7) * 32;
      const size_t go = ((size_t)b * L_ + m0 + r) * C_ + seg;
      const ushort* sh = kTh + go;
      const ushort* sl = kTl + go;
      short8 t0 = *(const short8*)(sh);      short8 t1 = *(const short8*)(sh + 8);
      short8 t2 = *(const short8*)(sh + 16); short8 t3 = *(const short8*)(sh + 24);
      short8 u0 = *(const short8*)(sl);      short8 u1 = *(const short8*)(sl + 8);
      short8 u2 = *(const short8*)(sl + 16); short8 u3 = *(const short8*)(sl + 24);
      ushort* dh = &UNh[r*264 + seg];
      ushort* dl = &UNl[r*264 + seg];
      *(short8*)(dh)      = t0; *(short8*)(dh + 8)  = t1;
      *(short8*)(dh + 16) = t2; *(short8*)(dh + 24) = t3;
      *(short8*)(dl)      = u0; *(short8*)(dl + 8)  = u1;
      *(short8*)(dl + 16) = u2; *(short8*)(dl + 24) = u3;
      if (tid < 32) {
        float pmv = mask[(size_t)b * L_ + m0 + tid];
        pmS[tid] = pmv;
        lmS[tid] = logf(pmv + 1e-6f);
      }
    }
    __syncthreads();

    // ---- QK^T (swapped): S^T[kv][q] = mfma(K, Q) ----
    floatx4 s0 = {0,0,0,0}, s1 = {0,0,0,0};
#pragma unroll
    for (int kc = 0; kc < 8; ++kc) {
      const int o0 = lr*264 + kc*32 + g*8;
      const int o1 = (16+lr)*264 + kc*32 + g*8;
      short8 ah0 = *(const short8*)&UNh[o0];
      short8 ah1 = *(const short8*)&UNh[o1];
      short8 al0 = *(const short8*)&UNl[o0];
      short8 al1 = *(const short8*)&UNl[o1];
      s0 = MFMA16(ah0, qfh[kc], s0, 0, 0, 0);
      s0 = MFMA16(ah0, qfl[kc], s0, 0, 0, 0);
      s0 = MFMA16(al0, qfh[kc], s0, 0, 0, 0);
      s1 = MFMA16(ah1, qfh[kc], s1, 0, 0, 0);
      s1 = MFMA16(ah1, qfl[kc], s1, 0, 0, 0);
      s1 = MFMA16(al1, qfh[kc], s1, 0, 0, 0);
    }

    // ---- online softmax piece (lane = q-row q0+16w+lr; kv = 4g+r / 16+4g+r) ----
    float sv0[4], sv1[4];
#pragma unroll
    for (int r = 0; r < 4; ++r) {
      sv0[r] = s0[r] + lmS[4*g + r];
      sv1[r] = s1[r] + lmS[16 + 4*g + r];
    }
    float mt = sv0[0];
#pragma unroll
    for (int r = 1; r < 4; ++r) mt = fmaxf(mt, sv0[r]);
#pragma unroll
    for (int r = 0; r < 4; ++r) mt = fmaxf(mt, sv1[r]);
    mt = fmaxf(mt, __shfl_xor(mt, 16));
    mt = fmaxf(mt, __shfl_xor(mt, 32));

    const int trig = (__all(mt <= M + 8.0f) == 0) ? 1 : 0;
    float cor = 1.0f;
    if (trig) {
      float Mn = fmaxf(M, mt);
      cor = __expf(M - Mn);
      Sp *= cor;
      M = Mn;
    }
    if (lane < 16) corS[16*w + lane] = cor;
    if (lane == 0) flagS[w] = trig;

    ushort4 ph0, pl0, ph1, pl1;
#pragma unroll
    for (int r = 0; r < 4; ++r) {
      float p0 = __expf(sv0[r] - M);
      float p1 = __expf(sv1[r] - M);
      Sp += p0 + p1;
      float q0v = p0 * pmS[4*g + r];
      float q1v = p1 * pmS[16 + 4*g + r];
      ushort h, l;
      split2(q0v, h, l); ((ushort*)&ph0)[r] = h; ((ushort*)&pl0)[r] = l;
      split2(q1v, h, l); ((ushort*)&ph1)[r] = h; ((ushort*)&pl1)[r] = l;
    }
    {
      const int prow = (16*w + lr) * 40;
      *(ushort4*)&Ph[prow + 4*g]      = ph0;
      *(ushort4*)&Ph[prow + 16 + 4*g] = ph1;
      *(ushort4*)&Pl[prow + 4*g]      = pl0;
      *(ushort4*)&Pl[prow + 16 + 4*g] = pl1;
    }
    __syncthreads();   // P ready; K reads done

    // ---- stage V-tile [256][40] into union (overwrites K) ----
    {
      const size_t go = ((size_t)b * C_ + tid) * L_ + m0;
      const ushort* sh = vh + go;
      const ushort* sl = vl + go;
      short8 t0 = *(const short8*)(sh);      short8 t1 = *(const short8*)(sh + 8);
      short8 t2 = *(const short8*)(sh + 16); short8 t3 = *(const short8*)(sh + 24);
      short8 u0 = *(const short8*)(sl);      short8 u1 = *(const short8*)(sl + 8);
      short8 u2 = *(const short8*)(sl + 16); short8 u3 = *(const short8*)(sl + 24);
      ushort* dh = &UNh[tid*40];
      ushort* dl = &UNl[tid*40];
      *(short8*)(dh)      = t0; *(short8*)(dh + 8)  = t1;
      *(short8*)(dh + 16) = t2; *(short8*)(dh + 24) = t3;
      *(short8*)(dl)      = u0; *(short8*)(dl + 8)  = u1;
      *(short8*)(dl + 16) = u2; *(short8*)(dl + 24) = u3;
    }
    __syncthreads();

    // ---- PV: O[64 rows][c-slice 64w..+63] ----
    const int anyf = flagS[0] | flagS[1] | flagS[2] | flagS[3];
    if (anyf) {
#pragma unroll
      for (int rf = 0; rf < 4; ++rf) {
        float4 c4 = *(const float4*)&corS[16*rf + 4*g];
#pragma unroll
        for (int cf = 0; cf < 4; ++cf) {
          O[rf][cf][0] *= c4.x; O[rf][cf][1] *= c4.y;
          O[rf][cf][2] *= c4.z; O[rf][cf][3] *= c4.w;
        }
      }
    }
    short8 pfh[4], pfl[4];
#pragma unroll
    for (int rf = 0; rf < 4; ++rf) {
      const int o = (16*rf + lr)*40 + g*8;
      pfh[rf] = *(const short8*)&Ph[o];
      pfl[rf] = *(const short8*)&Pl[o];
    }
#pragma unroll
    for (int cf = 0; cf < 4; ++cf) {
      const int o = (64*w + 16*cf + lr)*40 + g*8;
      short8 vfh = *(const short8*)&UNh[o];
      short8 vfl = *(const short8*)&UNl[o];
#pragma unroll
      for (int rf = 0; rf < 4; ++rf) {
        O[rf][cf] = MFMA16(pfh[rf], vfh, O[rf][cf], 0, 0, 0);
        O[rf][cf] = MFMA16(pfh[rf], vfl, O[rf][cf], 0, 0, 0);
        O[rf][cf] = MFMA16(pfl[rf], vfh, O[rf][cf], 0, 0, 0);
      }
    }
    __syncthreads();   // V/P reads done before next-step overwrite
  }

  // ---- epilogue ----
  Sp += __shfl_xor(Sp, 16);
  Sp += __shfl_xor(Sp, 32);
  {
    const size_t srow = ((size_t)(ks*8 + b)) * L_ + q0 + 16*w + lr;
    if (lane < 16) { Mstat[srow] = M; Sstat[srow] = Sp; }
  }
#pragma unroll
  for (int rf = 0; rf < 4; ++rf) {
#pragma unroll
    for (int r = 0; r < 4; ++r) {
      const size_t row = ((size_t)(ks*8 + b)) * L_ + q0 + 16*rf + 4*g + r;
      float* op = &Opart[row * C_ + 64*w + lr];
#pragma unroll
      for (int cf = 0; cf < 4; ++cf) op[16*cf] = O[rf][cf][r];
    }
  }
}

// ---------------------------------------------------------------------------
// Merge kv-splits, normalize, relu, split-bf16 -> hT (B,L,C).
// One wave per row; 4096 blocks x 256 threads.
// ---------------------------------------------------------------------------
__global__ __launch_bounds__(256) void merge_kernel(
    const float* __restrict__ Opart, const float* __restrict__ Mstat,
    const float* __restrict__ Sstat,
    ushort* __restrict__ hTh, ushort* __restrict__ hTl)
{
  const int w = threadIdx.x >> 6, lane = threadIdx.x & 63;
  const size_t row = (size_t)blockIdx.x * 4 + w;
  const size_t n = (size_t)B_ * L_;
  const float M1 = Mstat[row],     M2 = Mstat[n + row];
  const float S1 = Sstat[row],     S2 = Sstat[n + row];
  const float M  = fmaxf(M1, M2);
  const float w1 = __expf(M1 - M), w2 = __expf(M2 - M);
  const float inv = 1.0f / (w1*S1 + w2*S2);
  float4 a = *(const float4*)&Opart[row * C_ + lane*4];
  float4 c = *(const float4*)&Opart[(n + row) * C_ + lane*4];
  float hv[4];
  hv[0] = fmaxf((w1*a.x + w2*c.x) * inv, 0.f);
  hv[1] = fmaxf((w1*a.y + w2*c.y) * inv, 0.f);
  hv[2] = fmaxf((w1*a.z + w2*c.z) * inv, 0.f);
  hv[3] = fmaxf((w1*a.w + w2*c.w) * inv, 0.f);
  ushort h[4], l[4];
#pragma unroll
  for (int j = 0; j < 4; ++j) split2(hv[j], h[j], l[j]);
  const size_t o = row * C_ + lane*4;
  *(ushort4*)&hTh[o] = make_ushort4(h[0], h[1], h[2], h[3]);
  *(ushort4*)&hTl[o] = make_ushort4(l[0], l[1], l[2], l[3]);
}

// ---------------------------------------------------------------------------
extern "C" void kernel_launch(void* const* d_in, const int* in_sizes, int n_in,
                              void* d_out, int out_size, void* d_ws, size_t ws_size,
                              hipStream_t stream) {
  (void)in_sizes; (void)n_in; (void)out_size; (void)ws_size;
  const float* x1   = (const float*)d_in[0];
  const float* mask = (const float*)d_in[2];
  const float* Wq   = (const float*)d_in[3];
  const float* bq   = (const float*)d_in[4];
  const float* Wk   = (const float*)d_in[5];
  const float* bk   = (const float*)d_in[6];
  const float* Wv   = (const float*)d_in[7];
  const float* bv   = (const float*)d_in[8];
  const float* Wo   = (const float*)d_in[9];
  const float* bo   = (const float*)d_in[10];
  float* out = (float*)d_out;
  uint8_t* w8 = (uint8_t*)d_ws;

  ushort* x1Th = (ushort*)(w8);                      // 16777216 B
  ushort* x1Tl = (ushort*)(w8 + 16777216);           // 16777216
  ushort* qTh  = (ushort*)(w8 + 33554432);           // 8388608 each
  ushort* qTl  = (ushort*)(w8 + 41943040);
  ushort* kTh  = (ushort*)(w8 + 50331648);
  ushort* kTl  = (ushort*)(w8 + 58720256);
  ushort* vh   = (ushort*)(w8 + 67108864);
  ushort* vl   = (ushort*)(w8 + 75497472);
  ushort* wb   = (ushort*)(w8 + 83886080);           // 2097152
  ushort* Wqh = wb;             ushort* Wql = wb + 131072;
  ushort* Wkh = wb + 262144;    ushort* Wkl = wb + 393216;
  ushort* Wvh = wb + 524288;    ushort* Wvl = wb + 655360;
  ushort* Woh = wb + 786432;    ushort* Wol = wb + 917504;
  float* Opart = (float*)(w8 + 85983232);            // 33554432
  float* Mstat = (float*)(w8 + 119537664);           // 131072
  float* Sstat = (float*)(w8 + 119668736);           // 131072
  ushort* hTh  = (ushort*)(w8 + 119799808);          // 8388608
  ushort* hTl  = (ushort*)(w8 + 128188416);          // 8388608

  // 1) x1 -> x1T split
  transpose_split_kernel<<<dim3(L_/32, D_/32, B_), 256, 0, stream>>>(x1, x1Th, x1Tl);
  // 2) weights split
  splitw_kernel<<<dim3(128, 1, 4), 256, 0, stream>>>(Wq, Wk, Wv, Wo, wb);
  // 3) qT = (x1T*Wq^T + bq) * 1/16   (L x C)
  mm_kernel<0><<<dim3(C_/128, L_/128, B_), 256, 0, stream>>>(
      x1Th, x1Tl, (long)L_*D_, D_, Wqh, Wql, 0, D_, D_,
      qTh, qTl, nullptr, (long)L_*C_, C_, bq, 0, nullptr, 0, 0.0625f);
  // 4) kT = x1T*Wk^T + bk
  mm_kernel<0><<<dim3(C_/128, L_/128, B_), 256, 0, stream>>>(
      x1Th, x1Tl, (long)L_*D_, D_, Wkh, Wkl, 0, D_, D_,
      kTh, kTl, nullptr, (long)L_*C_, C_, bk, 0, nullptr, 0, 1.0f);
  // 5) v = Wv*x1 + bv   (C x L)
  mm_kernel<1><<<dim3(L_/128, C_/128, B_), 256, 0, stream>>>(
      Wvh, Wvl, 0, D_, x1Th, x1Tl, (long)L_*D_, D_, D_,
      vh, vl, nullptr, (long)C_*L_, L_, bv, 0, nullptr, 0, 1.0f);
  // 6) flash attention (kv-split 2)
  flash_kernel<<<dim3(512), 256, 0, stream>>>(
      qTh, qTl, kTh, kTl, vh, vl, mask, Opart, Mstat, Sstat);
  // 7) merge + normalize + relu + split
  merge_kernel<<<dim3(B_*L_/4), 256, 0, stream>>>(Opart, Mstat, Sstat, hTh, hTl);
  // 8) out = (Wo*relu(h) + bo) * mask
  mm_kernel<4><<<dim3(L_/128, D_/128, B_), 256, 0, stream>>>(
      Woh, Wol, 0, C_, hTh, hTl, (long)L_*C_, C_, C_,
      nullptr, nullptr, out, (long)D_*L_, L_, bo, 0, mask, L_, 1.0f);
}

// Round 5
// 387.967 us; speedup vs baseline: 2.0297x; 1.0205x over previous
//
#include <hip/hip_runtime.h>
#include <hip/hip_bf16.h>
#include <cstdint>
#include <cstddef>

#define B_ 8
#define D_ 512
#define L_ 2048
#define C_ 256

typedef short short8 __attribute__((ext_vector_type(8)));
typedef float floatx4 __attribute__((ext_vector_type(4)));

#define MFMA16 __builtin_amdgcn_mfma_f32_16x16x32_bf16

__device__ __forceinline__ ushort bf16_of(float x) {
  union { float f; uint32_t u; } v; v.f = x;
  uint32_t r = v.u + 0x7fff + ((v.u >> 16) & 1);   // RNE
  return (ushort)(r >> 16);
}
__device__ __forceinline__ float f32_of(ushort h) {
  union { uint32_t u; float f; } v; v.u = ((uint32_t)h) << 16; return v.f;
}
__device__ __forceinline__ void split2(float x, ushort& h, ushort& l) {
  h = bf16_of(x);
  l = bf16_of(x - f32_of(h));
}

// ---------------------------------------------------------------------------
// Split-bf16 MFMA GEMM: D[m,n] = sum_k A[m,k]*B[n,k] (both k-contig)
// EPI 0: split-out, v=(acc+bias[col])*scale    (qT with scale=1/16, kT)
// EPI 1: split-out, v= acc+bias[row]           (v)
// EPI 4: f32 out, v=(acc+aux1[row])*aux2[col]  (final proj)
// ---------------------------------------------------------------------------
template<int EPI>
__global__ __launch_bounds__(256) void mm_kernel(
    const ushort* __restrict__ Ah, const ushort* __restrict__ Al, long sA, int lda,
    const ushort* __restrict__ Bh, const ushort* __restrict__ Bl, long sB, int ldb,
    int K,
    ushort* __restrict__ o1, ushort* __restrict__ o2, float* __restrict__ of,
    long sO, int ldo,
    const float* __restrict__ aux1, long saux1,
    const float* __restrict__ aux2, long saux2, float scale)
{
  const int b = blockIdx.z;
  Ah += (long)b * sA;  Al += (long)b * sA;
  Bh += (long)b * sB;  Bl += (long)b * sB;
  const int m0 = blockIdx.y * 128, n0 = blockIdx.x * 128;

  __shared__ ushort Ash[128][40], Asl[128][40], Bsh[128][40], Bsl[128][40];

  const int tid = threadIdx.x;
  const int wv = tid >> 6, lane = tid & 63;
  const int wm = (wv >> 1) * 64, wn = (wv & 1) * 64;
  const int lr = lane & 15, lg = lane >> 4;

  floatx4 acc[4][4] = {};

  const int srow = tid >> 1;
  const int sc   = (tid & 1) * 8;

  for (int k0 = 0; k0 < K; k0 += 32) {
    const ushort* pAh = Ah + (size_t)(m0 + srow) * lda + k0;
    const ushort* pAl = Al + (size_t)(m0 + srow) * lda + k0;
    const ushort* pBh = Bh + (size_t)(n0 + srow) * ldb + k0;
    const ushort* pBl = Bl + (size_t)(n0 + srow) * ldb + k0;
    short8 a0 = *(const short8*)(pAh + sc);
    short8 a1 = *(const short8*)(pAh + sc + 16);
    short8 a2 = *(const short8*)(pAl + sc);
    short8 a3 = *(const short8*)(pAl + sc + 16);
    short8 b0 = *(const short8*)(pBh + sc);
    short8 b1 = *(const short8*)(pBh + sc + 16);
    short8 b2 = *(const short8*)(pBl + sc);
    short8 b3 = *(const short8*)(pBl + sc + 16);
    __syncthreads();
    *(short8*)&Ash[srow][sc]      = a0;
    *(short8*)&Ash[srow][sc + 16] = a1;
    *(short8*)&Asl[srow][sc]      = a2;
    *(short8*)&Asl[srow][sc + 16] = a3;
    *(short8*)&Bsh[srow][sc]      = b0;
    *(short8*)&Bsh[srow][sc + 16] = b1;
    *(short8*)&Bsl[srow][sc]      = b2;
    *(short8*)&Bsl[srow][sc + 16] = b3;
    __syncthreads();

    short8 fah[4], fal[4], fbh[4], fbl[4];
#pragma unroll
    for (int i = 0; i < 4; ++i) {
      fah[i] = *(const short8*)&Ash[wm + i*16 + lr][lg*8];
      fal[i] = *(const short8*)&Asl[wm + i*16 + lr][lg*8];
      fbh[i] = *(const short8*)&Bsh[wn + i*16 + lr][lg*8];
      fbl[i] = *(const short8*)&Bsl[wn + i*16 + lr][lg*8];
    }
#pragma unroll
    for (int i = 0; i < 4; ++i)
#pragma unroll
      for (int j = 0; j < 4; ++j) {
        acc[i][j] = MFMA16(fah[i], fbh[j], acc[i][j], 0, 0, 0);
        acc[i][j] = MFMA16(fah[i], fbl[j], acc[i][j], 0, 0, 0);
        acc[i][j] = MFMA16(fal[i], fbh[j], acc[i][j], 0, 0, 0);
      }
  }

  const long ooff = (long)b * sO;
#pragma unroll
  for (int i = 0; i < 4; ++i) {
#pragma unroll
    for (int j = 0; j < 4; ++j) {
#pragma unroll
      for (int r = 0; r < 4; ++r) {
        const int row = m0 + wm + i*16 + lg*4 + r;
        const int col = n0 + wn + j*16 + lr;
        float v = acc[i][j][r];
        const long oidx = ooff + (long)row * ldo + col;
        if constexpr (EPI == 0) {
          v = (v + aux1[(long)b * saux1 + col]) * scale;
          ushort h, l; split2(v, h, l); o1[oidx] = h; o2[oidx] = l;
        } else if constexpr (EPI == 1) {
          v += aux1[(long)b * saux1 + row];
          ushort h, l; split2(v, h, l); o1[oidx] = h; o2[oidx] = l;
        } else {
          of[oidx] = (v + aux1[(long)b * saux1 + row]) * aux2[(long)b * saux2 + col];
        }
      }
    }
  }
}

// ---------------------------------------------------------------------------
// x1 (B,D,L) f32 -> x1T (B,L,D) split bf16.
// ---------------------------------------------------------------------------
__global__ __launch_bounds__(256) void transpose_split_kernel(
    const float* __restrict__ x1, ushort* __restrict__ th, ushort* __restrict__ tl)
{
  __shared__ float t[32][33];
  const int b = blockIdx.z;
  const int l0 = blockIdx.x * 32, d0 = blockIdx.y * 32;
  const int tid = threadIdx.x;
  const int dr = tid >> 3, l4 = (tid & 7) * 4;
  float4 v = *(const float4*)(x1 + ((size_t)b * D_ + d0 + dr) * L_ + l0 + l4);
  t[dr][l4+0] = v.x; t[dr][l4+1] = v.y; t[dr][l4+2] = v.z; t[dr][l4+3] = v.w;
  __syncthreads();
  const int lr = tid >> 3, d4 = (tid & 7) * 4;
  ushort hh[4], ll[4];
#pragma unroll
  for (int j = 0; j < 4; ++j) split2(t[d4+j][lr], hh[j], ll[j]);
  const size_t o = ((size_t)b * L_ + l0 + lr) * D_ + d0 + d4;
  *(ushort4*)&th[o] = make_ushort4(hh[0], hh[1], hh[2], hh[3]);
  *(ushort4*)&tl[o] = make_ushort4(ll[0], ll[1], ll[2], ll[3]);
}

__global__ __launch_bounds__(256) void splitw_kernel(
    const float* __restrict__ w0, const float* __restrict__ w1,
    const float* __restrict__ w2, const float* __restrict__ w3,
    ushort* __restrict__ wbase)
{
  const int z = blockIdx.z;
  const float* s = (z == 0) ? w0 : (z == 1) ? w1 : (z == 2) ? w2 : w3;
  ushort* dh = wbase + (size_t)z * 262144;
  ushort* dl = dh + 131072;
  const int i = (blockIdx.x * 256 + threadIdx.x) * 4;
  float4 v = *(const float4*)(s + i);
  ushort h[4], l[4];
  split2(v.x, h[0], l[0]); split2(v.y, h[1], l[1]);
  split2(v.z, h[2], l[2]); split2(v.w, h[3], l[3]);
  *(ushort4*)&dh[i] = make_ushort4(h[0], h[1], h[2], h[3]);
  *(ushort4*)&dl[i] = make_ushort4(l[0], l[1], l[2], l[3]);
}

// ---------------------------------------------------------------------------
// Flash attention v2: S=qk^T(pre-scaled)+log(pm+1e-6), online softmax, O=P*pm*V.
// Block: 64 q-rows, 4 waves, KVBLK=32, kv-split 2.
// - K: single LDS buffer [32][256] hi/lo, XOR-swizzled (chunk^=row&7),
//      register-prefetched one step ahead (loads at top, ds_write after P-sync).
// - V: no LDS; B-fragments prefetched one step ahead straight from global/L2.
// - P: through LDS [64][40] hi/lo (cross-wave: QK is q-split, PV is c-split).
// - 2 barriers/step.
// ---------------------------------------------------------------------------
__global__ __launch_bounds__(256, 2) void flash_kernel(
    const ushort* __restrict__ qTh, const ushort* __restrict__ qTl,
    const ushort* __restrict__ kTh, const ushort* __restrict__ kTl,
    const ushort* __restrict__ vh,  const ushort* __restrict__ vl,
    const float* __restrict__ mask,
    float* __restrict__ Opart, float* __restrict__ Mstat, float* __restrict__ Sstat)
{
  __shared__ __align__(16) ushort Kh[32*256], Kl[32*256];
  __shared__ __align__(16) ushort Ph[2560], Pl[2560];   // [64][40]
  __shared__ float lmS[32], pmS[32], corS[64];
  __shared__ int flagS[4];

  const int f = blockIdx.x;
  const int b = f & 7, ks = (f >> 3) & 1, qt = f >> 4;
  const int q0 = qt * 64;
  const int tid = threadIdx.x;
  const int w = tid >> 6, lane = tid & 63;
  const int lr = lane & 15, g = lane >> 4;
  const int sr = tid >> 3;            // staging row 0..31
  const int sc0 = (tid & 7) * 4;      // staging 16B-chunk base 0..28
  const int lswz = lr & 7;

  // Q fragments (B-operand): q-row = q0+16w+lr, k-chunks 0..7
  short8 qfh[8], qfl[8];
  {
    const size_t qoff = ((size_t)b * L_ + q0 + 16*w + lr) * C_ + g*8;
    const ushort* ph = qTh + qoff;
    const ushort* pl = qTl + qoff;
#pragma unroll
    for (int kc = 0; kc < 8; ++kc) {
      qfh[kc] = *(const short8*)(ph + kc*32);
      qfl[kc] = *(const short8*)(pl + kc*32);
    }
  }

  floatx4 O[4][4] = {};             // [row-frag][c-frag], c-slice = 64*w
  float M = -3.0e38f, Sp = 0.f;

  const int kvbase = ks * 1024;

  short8 kpre[8];   // K prefetch: hi j=0..3, lo j=4..7
  short8 vpre[8];   // V prefetch: hi cf=0..3, lo cf=4..7

  // ---- prologue: K(0), V(0), mask(0) ----
  {
    const size_t ro = ((size_t)b * L_ + kvbase + sr) * C_;
#pragma unroll
    for (int j = 0; j < 4; ++j) {
      kpre[j]   = *(const short8*)(kTh + ro + (size_t)(sc0 + j) * 8);
      kpre[4+j] = *(const short8*)(kTl + ro + (size_t)(sc0 + j) * 8);
    }
  }
#pragma unroll
  for (int cf = 0; cf < 4; ++cf) {
    const size_t vr = ((size_t)b * C_ + 64*w + 16*cf + lr) * L_ + kvbase + 8*g;
    vpre[cf]   = *(const short8*)(vh + vr);
    vpre[4+cf] = *(const short8*)(vl + vr);
  }
  if (tid < 32) {
    float pmv = mask[(size_t)b * L_ + kvbase + tid];
    pmS[tid] = pmv; lmS[tid] = __logf(pmv + 1e-6f);
  }
#pragma unroll
  for (int j = 0; j < 4; ++j) {
    const int p = (sc0 + j) ^ (sr & 7);
    *(short8*)&Kh[sr*256 + p*8] = kpre[j];
    *(short8*)&Kl[sr*256 + p*8] = kpre[4+j];
  }
  __syncthreads();

  for (int step = 0; step < 32; ++step) {
    const int m1 = kvbase + ((step + 1) & 31) * 32;   // next tile (wraps; dummy on last)

    // ---- issue K(s+1) global loads (consumed after P-sync) ----
    {
      const size_t ro = ((size_t)b * L_ + m1 + sr) * C_;
#pragma unroll
      for (int j = 0; j < 4; ++j) {
        kpre[j]   = *(const short8*)(kTh + ro + (size_t)(sc0 + j) * 8);
        kpre[4+j] = *(const short8*)(kTl + ro + (size_t)(sc0 + j) * 8);
      }
    }

    // ---- QK^T (swapped): S^T[kv][q] = mfma(K, Q), swizzled K reads ----
    floatx4 s0 = {0,0,0,0}, s1 = {0,0,0,0};
#pragma unroll
    for (int kc = 0; kc < 8; ++kc) {
      const int p  = ((4*kc + g) ^ lswz) * 8;
      const int o0 = lr*256 + p;
      const int o1 = o0 + 16*256;
      short8 ah0 = *(const short8*)&Kh[o0];
      short8 ah1 = *(const short8*)&Kh[o1];
      short8 al0 = *(const short8*)&Kl[o0];
      short8 al1 = *(const short8*)&Kl[o1];
      s0 = MFMA16(ah0, qfh[kc], s0, 0, 0, 0);
      s0 = MFMA16(ah0, qfl[kc], s0, 0, 0, 0);
      s0 = MFMA16(al0, qfh[kc], s0, 0, 0, 0);
      s1 = MFMA16(ah1, qfh[kc], s1, 0, 0, 0);
      s1 = MFMA16(ah1, qfl[kc], s1, 0, 0, 0);
      s1 = MFMA16(al1, qfh[kc], s1, 0, 0, 0);
    }

    // ---- online softmax (lane = q-row q0+16w+lr; kv = 4g+r / 16+4g+r) ----
    float sv0[4], sv1[4];
#pragma unroll
    for (int r = 0; r < 4; ++r) {
      sv0[r] = s0[r] + lmS[4*g + r];
      sv1[r] = s1[r] + lmS[16 + 4*g + r];
    }
    float mt = sv0[0];
#pragma unroll
    for (int r = 1; r < 4; ++r) mt = fmaxf(mt, sv0[r]);
#pragma unroll
    for (int r = 0; r < 4; ++r) mt = fmaxf(mt, sv1[r]);
    mt = fmaxf(mt, __shfl_xor(mt, 16));
    mt = fmaxf(mt, __shfl_xor(mt, 32));

    const int trig = (__all(mt <= M + 8.0f) == 0) ? 1 : 0;
    float cor = 1.0f;
    if (trig) {
      float Mn = fmaxf(M, mt);
      cor = __expf(M - Mn);
      Sp *= cor;
      M = Mn;
    }
    if (lane < 16) corS[16*w + lane] = cor;
    if (lane == 0) flagS[w] = trig;

    ushort4 ph0, pl0, ph1, pl1;
#pragma unroll
    for (int r = 0; r < 4; ++r) {
      float p0 = __expf(sv0[r] - M);
      float p1 = __expf(sv1[r] - M);
      Sp += p0 + p1;
      float q0v = p0 * pmS[4*g + r];
      float q1v = p1 * pmS[16 + 4*g + r];
      ushort h, l;
      split2(q0v, h, l); ((ushort*)&ph0)[r] = h; ((ushort*)&pl0)[r] = l;
      split2(q1v, h, l); ((ushort*)&ph1)[r] = h; ((ushort*)&pl1)[r] = l;
    }
    {
      const int prow = (16*w + lr) * 40;
      *(ushort4*)&Ph[prow + 4*g]      = ph0;
      *(ushort4*)&Ph[prow + 16 + 4*g] = ph1;
      *(ushort4*)&Pl[prow + 4*g]      = pl0;
      *(ushort4*)&Pl[prow + 16 + 4*g] = pl1;
    }
    __syncthreads();   // P-sync: P visible; K(s) reads done; kpre arrived

    // ---- tail writes: K(s+1) -> LDS (swizzled), mask(s+1) -> LDS ----
#pragma unroll
    for (int j = 0; j < 4; ++j) {
      const int p = (sc0 + j) ^ (sr & 7);
      *(short8*)&Kh[sr*256 + p*8] = kpre[j];
      *(short8*)&Kl[sr*256 + p*8] = kpre[4+j];
    }
    if (tid < 32) {
      float pmv = mask[(size_t)b * L_ + m1 + tid];
      pmS[tid] = pmv; lmS[tid] = __logf(pmv + 1e-6f);
    }

    // ---- PV: O[64 q-rows][c-slice 64w..+63], V from registers ----
    const int anyf = flagS[0] | flagS[1] | flagS[2] | flagS[3];
    if (anyf) {
#pragma unroll
      for (int rf = 0; rf < 4; ++rf) {
        float4 c4 = *(const float4*)&corS[16*rf + 4*g];
#pragma unroll
        for (int cf = 0; cf < 4; ++cf) {
          O[rf][cf][0] *= c4.x; O[rf][cf][1] *= c4.y;
          O[rf][cf][2] *= c4.z; O[rf][cf][3] *= c4.w;
        }
      }
    }
    short8 pfh[4], pfl[4];
#pragma unroll
    for (int rf = 0; rf < 4; ++rf) {
      const int o = (16*rf + lr)*40 + g*8;
      pfh[rf] = *(const short8*)&Ph[o];
      pfl[rf] = *(const short8*)&Pl[o];
    }
#pragma unroll
    for (int cf = 0; cf < 4; ++cf) {
#pragma unroll
      for (int rf = 0; rf < 4; ++rf) {
        O[rf][cf] = MFMA16(pfh[rf], vpre[cf],   O[rf][cf], 0, 0, 0);
        O[rf][cf] = MFMA16(pfh[rf], vpre[4+cf], O[rf][cf], 0, 0, 0);
        O[rf][cf] = MFMA16(pfl[rf], vpre[cf],   O[rf][cf], 0, 0, 0);
      }
    }

    // ---- issue V(s+1) global loads (after last vpre use) ----
#pragma unroll
    for (int cf = 0; cf < 4; ++cf) {
      const size_t vr = ((size_t)b * C_ + 64*w + 16*cf + lr) * L_ + m1 + 8*g;
      vpre[cf]   = *(const short8*)(vh + vr);
      vpre[4+cf] = *(const short8*)(vl + vr);
    }
    __syncthreads();   // end: K(s+1)/mask(s+1) visible; P reads done
  }

  // ---- epilogue ----
  Sp += __shfl_xor(Sp, 16);
  Sp += __shfl_xor(Sp, 32);
  {
    const size_t srw = ((size_t)(ks*8 + b)) * L_ + q0 + 16*w + lr;
    if (lane < 16) { Mstat[srw] = M; Sstat[srw] = Sp; }
  }
#pragma unroll
  for (int rf = 0; rf < 4; ++rf) {
#pragma unroll
    for (int r = 0; r < 4; ++r) {
      const size_t row = ((size_t)(ks*8 + b)) * L_ + q0 + 16*rf + 4*g + r;
      float* op = &Opart[row * C_ + 64*w + lr];
#pragma unroll
      for (int cf = 0; cf < 4; ++cf) op[16*cf] = O[rf][cf][r];
    }
  }
}

// ---------------------------------------------------------------------------
// Merge kv-splits, normalize, relu, split-bf16 -> hT (B,L,C).
// ---------------------------------------------------------------------------
__global__ __launch_bounds__(256) void merge_kernel(
    const float* __restrict__ Opart, const float* __restrict__ Mstat,
    const float* __restrict__ Sstat,
    ushort* __restrict__ hTh, ushort* __restrict__ hTl)
{
  const int w = threadIdx.x >> 6, lane = threadIdx.x & 63;
  const size_t row = (size_t)blockIdx.x * 4 + w;
  const size_t n = (size_t)B_ * L_;
  const float M1 = Mstat[row],     M2 = Mstat[n + row];
  const float S1 = Sstat[row],     S2 = Sstat[n + row];
  const float M  = fmaxf(M1, M2);
  const float w1 = __expf(M1 - M), w2 = __expf(M2 - M);
  const float inv = 1.0f / (w1*S1 + w2*S2);
  float4 a = *(const float4*)&Opart[row * C_ + lane*4];
  float4 c = *(const float4*)&Opart[(n + row) * C_ + lane*4];
  float hv[4];
  hv[0] = fmaxf((w1*a.x + w2*c.x) * inv, 0.f);
  hv[1] = fmaxf((w1*a.y + w2*c.y) * inv, 0.f);
  hv[2] = fmaxf((w1*a.z + w2*c.z) * inv, 0.f);
  hv[3] = fmaxf((w1*a.w + w2*c.w) * inv, 0.f);
  ushort h[4], l[4];
#pragma unroll
  for (int j = 0; j < 4; ++j) split2(hv[j], h[j], l[j]);
  const size_t o = row * C_ + lane*4;
  *(ushort4*)&hTh[o] = make_ushort4(h[0], h[1], h[2], h[3]);
  *(ushort4*)&hTl[o] = make_ushort4(l[0], l[1], l[2], l[3]);
}

// ---------------------------------------------------------------------------
extern "C" void kernel_launch(void* const* d_in, const int* in_sizes, int n_in,
                              void* d_out, int out_size, void* d_ws, size_t ws_size,
                              hipStream_t stream) {
  (void)in_sizes; (void)n_in; (void)out_size; (void)ws_size;
  const float* x1   = (const float*)d_in[0];
  const float* mask = (const float*)d_in[2];
  const float* Wq   = (const float*)d_in[3];
  const float* bq   = (const float*)d_in[4];
  const float* Wk   = (const float*)d_in[5];
  const float* bk   = (const float*)d_in[6];
  const float* Wv   = (const float*)d_in[7];
  const float* bv   = (const float*)d_in[8];
  const float* Wo   = (const float*)d_in[9];
  const float* bo   = (const float*)d_in[10];
  float* out = (float*)d_out;
  uint8_t* w8 = (uint8_t*)d_ws;

  ushort* x1Th = (ushort*)(w8);                      // 16777216 B
  ushort* x1Tl = (ushort*)(w8 + 16777216);           // 16777216
  ushort* qTh  = (ushort*)(w8 + 33554432);           // 8388608 each
  ushort* qTl  = (ushort*)(w8 + 41943040);
  ushort* kTh  = (ushort*)(w8 + 50331648);
  ushort* kTl  = (ushort*)(w8 + 58720256);
  ushort* vh   = (ushort*)(w8 + 67108864);
  ushort* vl   = (ushort*)(w8 + 75497472);
  ushort* wb   = (ushort*)(w8 + 83886080);           // 2097152
  ushort* Wqh = wb;             ushort* Wql = wb + 131072;
  ushort* Wkh = wb + 262144;    ushort* Wkl = wb + 393216;
  ushort* Wvh = wb + 524288;    ushort* Wvl = wb + 655360;
  ushort* Woh = wb + 786432;    ushort* Wol = wb + 917504;
  float* Opart = (float*)(w8 + 85983232);            // 33554432
  float* Mstat = (float*)(w8 + 119537664);           // 131072
  float* Sstat = (float*)(w8 + 119668736);           // 131072
  ushort* hTh  = (ushort*)(w8 + 119799808);          // 8388608
  ushort* hTl  = (ushort*)(w8 + 128188416);          // 8388608

  // 1) x1 -> x1T split
  transpose_split_kernel<<<dim3(L_/32, D_/32, B_), 256, 0, stream>>>(x1, x1Th, x1Tl);
  // 2) weights split
  splitw_kernel<<<dim3(128, 1, 4), 256, 0, stream>>>(Wq, Wk, Wv, Wo, wb);
  // 3) qT = (x1T*Wq^T + bq) * 1/16   (L x C)
  mm_kernel<0><<<dim3(C_/128, L_/128, B_), 256, 0, stream>>>(
      x1Th, x1Tl, (long)L_*D_, D_, Wqh, Wql, 0, D_, D_,
      qTh, qTl, nullptr, (long)L_*C_, C_, bq, 0, nullptr, 0, 0.0625f);
  // 4) kT = x1T*Wk^T + bk
  mm_kernel<0><<<dim3(C_/128, L_/128, B_), 256, 0, stream>>>(
      x1Th, x1Tl, (long)L_*D_, D_, Wkh, Wkl, 0, D_, D_,
      kTh, kTl, nullptr, (long)L_*C_, C_, bk, 0, nullptr, 0, 1.0f);
  // 5) v = Wv*x1 + bv   (C x L)
  mm_kernel<1><<<dim3(L_/128, C_/128, B_), 256, 0, stream>>>(
      Wvh, Wvl, 0, D_, x1Th, x1Tl, (long)L_*D_, D_, D_,
      vh, vl, nullptr, (long)C_*L_, L_, bv, 0, nullptr, 0, 1.0f);
  // 6) flash attention (kv-split 2)
  flash_kernel<<<dim3(512), 256, 0, stream>>>(
      qTh, qTl, kTh, kTl, vh, vl, mask, Opart, Mstat, Sstat);
  // 7) merge + normalize + relu + split
  merge_kernel<<<dim3(B_*L_/4), 256, 0, stream>>>(Opart, Mstat, Sstat, hTh, hTl);
  // 8) out = (Wo*relu(h) + bo) * mask
  mm_kernel<4><<<dim3(L_/128, D_/128, B_), 256, 0, stream>>>(
      Woh, Wol, 0, C_, hTh, hTl, (long)L_*C_, C_, C_,
      nullptr, nullptr, out, (long)D_*L_, L_, bo, 0, mask, L_, 1.0f);
}

// Round 6
// 289.672 us; speedup vs baseline: 2.7184x; 1.3393x over previous
//
#include <hip/hip_runtime.h>
#include <hip/hip_bf16.h>
#include <cstdint>
#include <cstddef>

#define B_ 8
#define D_ 512
#define L_ 2048
#define C_ 256

typedef short short8 __attribute__((ext_vector_type(8)));
typedef float floatx4 __attribute__((ext_vector_type(4)));

#define MFMA16 __builtin_amdgcn_mfma_f32_16x16x32_bf16

__device__ __forceinline__ ushort bf16_of(float x) {
  union { float f; uint32_t u; } v; v.f = x;
  uint32_t r = v.u + 0x7fff + ((v.u >> 16) & 1);   // RNE
  return (ushort)(r >> 16);
}
__device__ __forceinline__ float f32_of(ushort h) {
  union { uint32_t u; float f; } v; v.u = ((uint32_t)h) << 16; return v.f;
}
__device__ __forceinline__ void split2(float x, ushort& h, ushort& l) {
  h = bf16_of(x);
  l = bf16_of(x - f32_of(h));
}

// ---------------------------------------------------------------------------
// Split-bf16 MFMA GEMM (unchanged from r5): D[m,n] = sum_k A[m,k]*B[n,k]
// EPI 0: split-out, v=(acc+bias[col])*scale    (qT with scale=1/16, kT)
// EPI 1: split-out, v= acc+bias[row]           (v)
// EPI 4: f32 out, v=(acc+aux1[row])*aux2[col]  (final proj)
// ---------------------------------------------------------------------------
template<int EPI>
__global__ __launch_bounds__(256) void mm_kernel(
    const ushort* __restrict__ Ah, const ushort* __restrict__ Al, long sA, int lda,
    const ushort* __restrict__ Bh, const ushort* __restrict__ Bl, long sB, int ldb,
    int K,
    ushort* __restrict__ o1, ushort* __restrict__ o2, float* __restrict__ of,
    long sO, int ldo,
    const float* __restrict__ aux1, long saux1,
    const float* __restrict__ aux2, long saux2, float scale)
{
  const int b = blockIdx.z;
  Ah += (long)b * sA;  Al += (long)b * sA;
  Bh += (long)b * sB;  Bl += (long)b * sB;
  const int m0 = blockIdx.y * 128, n0 = blockIdx.x * 128;

  __shared__ ushort Ash[128][40], Asl[128][40], Bsh[128][40], Bsl[128][40];

  const int tid = threadIdx.x;
  const int wv = tid >> 6, lane = tid & 63;
  const int wm = (wv >> 1) * 64, wn = (wv & 1) * 64;
  const int lr = lane & 15, lg = lane >> 4;

  floatx4 acc[4][4] = {};

  const int srow = tid >> 1;
  const int sc   = (tid & 1) * 8;

  for (int k0 = 0; k0 < K; k0 += 32) {
    const ushort* pAh = Ah + (size_t)(m0 + srow) * lda + k0;
    const ushort* pAl = Al + (size_t)(m0 + srow) * lda + k0;
    const ushort* pBh = Bh + (size_t)(n0 + srow) * ldb + k0;
    const ushort* pBl = Bl + (size_t)(n0 + srow) * ldb + k0;
    short8 a0 = *(const short8*)(pAh + sc);
    short8 a1 = *(const short8*)(pAh + sc + 16);
    short8 a2 = *(const short8*)(pAl + sc);
    short8 a3 = *(const short8*)(pAl + sc + 16);
    short8 b0 = *(const short8*)(pBh + sc);
    short8 b1 = *(const short8*)(pBh + sc + 16);
    short8 b2 = *(const short8*)(pBl + sc);
    short8 b3 = *(const short8*)(pBl + sc + 16);
    __syncthreads();
    *(short8*)&Ash[srow][sc]      = a0;
    *(short8*)&Ash[srow][sc + 16] = a1;
    *(short8*)&Asl[srow][sc]      = a2;
    *(short8*)&Asl[srow][sc + 16] = a3;
    *(short8*)&Bsh[srow][sc]      = b0;
    *(short8*)&Bsh[srow][sc + 16] = b1;
    *(short8*)&Bsl[srow][sc]      = b2;
    *(short8*)&Bsl[srow][sc + 16] = b3;
    __syncthreads();

    short8 fah[4], fal[4], fbh[4], fbl[4];
#pragma unroll
    for (int i = 0; i < 4; ++i) {
      fah[i] = *(const short8*)&Ash[wm + i*16 + lr][lg*8];
      fal[i] = *(const short8*)&Asl[wm + i*16 + lr][lg*8];
      fbh[i] = *(const short8*)&Bsh[wn + i*16 + lr][lg*8];
      fbl[i] = *(const short8*)&Bsl[wn + i*16 + lr][lg*8];
    }
#pragma unroll
    for (int i = 0; i < 4; ++i)
#pragma unroll
      for (int j = 0; j < 4; ++j) {
        acc[i][j] = MFMA16(fah[i], fbh[j], acc[i][j], 0, 0, 0);
        acc[i][j] = MFMA16(fah[i], fbl[j], acc[i][j], 0, 0, 0);
        acc[i][j] = MFMA16(fal[i], fbh[j], acc[i][j], 0, 0, 0);
      }
  }

  const long ooff = (long)b * sO;
#pragma unroll
  for (int i = 0; i < 4; ++i) {
#pragma unroll
    for (int j = 0; j < 4; ++j) {
#pragma unroll
      for (int r = 0; r < 4; ++r) {
        const int row = m0 + wm + i*16 + lg*4 + r;
        const int col = n0 + wn + j*16 + lr;
        float v = acc[i][j][r];
        const long oidx = ooff + (long)row * ldo + col;
        if constexpr (EPI == 0) {
          v = (v + aux1[(long)b * saux1 + col]) * scale;
          ushort h, l; split2(v, h, l); o1[oidx] = h; o2[oidx] = l;
        } else if constexpr (EPI == 1) {
          v += aux1[(long)b * saux1 + row];
          ushort h, l; split2(v, h, l); o1[oidx] = h; o2[oidx] = l;
        } else {
          of[oidx] = (v + aux1[(long)b * saux1 + row]) * aux2[(long)b * saux2 + col];
        }
      }
    }
  }
}

// ---------------------------------------------------------------------------
// x1 (B,D,L) f32 -> x1T (B,L,D) split bf16.  (unchanged)
// ---------------------------------------------------------------------------
__global__ __launch_bounds__(256) void transpose_split_kernel(
    const float* __restrict__ x1, ushort* __restrict__ th, ushort* __restrict__ tl)
{
  __shared__ float t[32][33];
  const int b = blockIdx.z;
  const int l0 = blockIdx.x * 32, d0 = blockIdx.y * 32;
  const int tid = threadIdx.x;
  const int dr = tid >> 3, l4 = (tid & 7) * 4;
  float4 v = *(const float4*)(x1 + ((size_t)b * D_ + d0 + dr) * L_ + l0 + l4);
  t[dr][l4+0] = v.x; t[dr][l4+1] = v.y; t[dr][l4+2] = v.z; t[dr][l4+3] = v.w;
  __syncthreads();
  const int lr = tid >> 3, d4 = (tid & 7) * 4;
  ushort hh[4], ll[4];
#pragma unroll
  for (int j = 0; j < 4; ++j) split2(t[d4+j][lr], hh[j], ll[j]);
  const size_t o = ((size_t)b * L_ + l0 + lr) * D_ + d0 + d4;
  *(ushort4*)&th[o] = make_ushort4(hh[0], hh[1], hh[2], hh[3]);
  *(ushort4*)&tl[o] = make_ushort4(ll[0], ll[1], ll[2], ll[3]);
}

__global__ __launch_bounds__(256) void splitw_kernel(
    const float* __restrict__ w0, const float* __restrict__ w1,
    const float* __restrict__ w2, const float* __restrict__ w3,
    ushort* __restrict__ wbase)
{
  const int z = blockIdx.z;
  const float* s = (z == 0) ? w0 : (z == 1) ? w1 : (z == 2) ? w2 : w3;
  ushort* dh = wbase + (size_t)z * 262144;
  ushort* dl = dh + 131072;
  const int i = (blockIdx.x * 256 + threadIdx.x) * 4;
  float4 v = *(const float4*)(s + i);
  ushort h[4], l[4];
  split2(v.x, h[0], l[0]); split2(v.y, h[1], l[1]);
  split2(v.z, h[2], l[2]); split2(v.w, h[3], l[3]);
  *(ushort4*)&dh[i] = make_ushort4(h[0], h[1], h[2], h[3]);
  *(ushort4*)&dl[i] = make_ushort4(l[0], l[1], l[2], l[3]);
}

// ---------------------------------------------------------------------------
// Flash attention v3: single-bf16 operands, fp32 accum/softmax.
// 256 blocks (1/CU) x 512 threads (8 waves). QBLK=128, KVBLK=64, kv-split 2.
// QK: waves = 2 kvh x 4 qh (each 32 kv x 32 q), Q in regs, K in dbuf LDS
//     (chunk-XOR swizzled), reg-staged one step ahead.
// PV: c-split (32 c per wave), V from global into regs, P via LDS [128][72].
// Block swizzle: the 16 q-tile blocks of one (b,ks) K/V stream share one XCD.
// ---------------------------------------------------------------------------
__global__ __launch_bounds__(512, 1) void flash_kernel(
    const ushort* __restrict__ qTh, const ushort* __restrict__ kTh,
    const ushort* __restrict__ vh,  const float* __restrict__ mask,
    float* __restrict__ Opart, float* __restrict__ Mstat, float* __restrict__ Sstat)
{
  __shared__ __align__(16) ushort Kbuf[2][64*256];   // 64 KB
  __shared__ __align__(16) ushort Pb[128*72];        // 18 KB
  __shared__ __align__(16) float mxS[2][128];
  __shared__ __align__(16) float ssS[2][128];
  __shared__ __align__(16) float corS[128];
  __shared__ __align__(16) float lmS[2][64], pmS[2][64];
  __shared__ int flagS[4];

  // block swizzle: f = xcd + 8*qt2; stream = xcd + 8*(qt2>>4); qt = qt2&15
  const int f = blockIdx.x;
  const int xcd = f & 7, qt2 = f >> 3;
  const int stream = xcd + 8 * (qt2 >> 4);           // 0..15
  const int b = stream >> 1, ks = stream & 1;
  const int qt = qt2 & 15;
  const int q0 = qt * 128;
  const int tid = threadIdx.x;
  const int wv = tid >> 6, lane = tid & 63;
  const int kvh = wv >> 2, qh = wv & 3;
  const int lr = lane & 15, g = lane >> 4;
  const int kvbase = ks * 1024;

  // Q fragments: q = q0 + 32*qh + 16*qi + lr, elements kc*32 + 8g.. (bf16 hi, pre-scaled 1/16)
  short8 qf[8][2];
#pragma unroll
  for (int kc = 0; kc < 8; ++kc)
#pragma unroll
    for (int qi = 0; qi < 2; ++qi)
      qf[kc][qi] = *(const short8*)(qTh + ((size_t)b*L_ + q0 + 32*qh + 16*qi + lr)*C_ + kc*32 + 8*g);

  floatx4 O[8][2] = {};
  float M[2]  = {-3.0e38f, -3.0e38f};
  float Sp[2] = {0.f, 0.f};

  // ---- prologue: stage K(0) (swizzled) + mask(0) ----
#pragma unroll
  for (int i = 0; i < 4; ++i) {
    const int Dc = i*512 + tid, row = Dc >> 5, c = Dc & 31;
    short8 kv8 = *(const short8*)(kTh + ((size_t)b*L_ + kvbase + row)*C_ + c*8);
    *(short8*)&Kbuf[0][row*256 + ((c ^ (row & 7)) * 8)] = kv8;
  }
  if (tid < 64) {
    float pmv = mask[(size_t)b*L_ + kvbase + tid];
    pmS[0][tid] = pmv; lmS[0][tid] = __logf(pmv + 1e-6f);
  }
  __syncthreads();

  for (int step = 0; step < 16; ++step) {
    const int cur = step & 1, nb = cur ^ 1;
    const int mcur  = kvbase + step * 64;
    const int mnext = kvbase + ((step + 1) & 15) * 64;

    // A) issue K(s+1) global loads into regs (consumed at G)
    short8 kreg[4];
#pragma unroll
    for (int i = 0; i < 4; ++i) {
      const int Dc = i*512 + tid, row = Dc >> 5, c = Dc & 31;
      kreg[i] = *(const short8*)(kTh + ((size_t)b*L_ + mnext + row)*C_ + c*8);
    }
    // B) V(s) loads into regs (consumed at H)
    short8 vf[2][2];
#pragma unroll
    for (int cf = 0; cf < 2; ++cf)
#pragma unroll
      for (int kh = 0; kh < 2; ++kh)
        vf[cf][kh] = *(const short8*)(vh + ((size_t)b*C_ + 32*wv + 16*cf + lr)*L_ + mcur + 32*kh + 8*g);
    float mnv = 0.f;
    if (tid < 64) mnv = mask[(size_t)b*L_ + mnext + tid];

    // C) QK^T (swapped): S^T[kv][q] = mfma(K, Q); wave covers its 32-kv half
    floatx4 sacc[2][2] = {};
#pragma unroll
    for (int kc = 0; kc < 8; ++kc) {
#pragma unroll
      for (int kh = 0; kh < 2; ++kh) {
        short8 a = *(const short8*)&Kbuf[cur][(32*kvh + 16*kh + lr)*256 + (((4*kc + g) ^ (lr & 7)) * 8)];
        sacc[kh][0] = MFMA16(a, qf[kc][0], sacc[kh][0], 0, 0, 0);
        sacc[kh][1] = MFMA16(a, qf[kc][1], sacc[kh][1], 0, 0, 0);
      }
    }

    // D) softmax partials over own 32 kv
    float sv[2][2][4];
    float4 lm0 = *(const float4*)&lmS[cur][32*kvh + 4*g];
    float4 lm1 = *(const float4*)&lmS[cur][32*kvh + 16 + 4*g];
#pragma unroll
    for (int r = 0; r < 4; ++r) {
      const float l0v = ((const float*)&lm0)[r], l1v = ((const float*)&lm1)[r];
      sv[0][0][r] = sacc[0][0][r] + l0v;
      sv[0][1][r] = sacc[0][1][r] + l0v;
      sv[1][0][r] = sacc[1][0][r] + l1v;
      sv[1][1][r] = sacc[1][1][r] + l1v;
    }
    float mt[2];
#pragma unroll
    for (int qi = 0; qi < 2; ++qi) {
      float m0 = fmaxf(fmaxf(sv[0][qi][0], sv[0][qi][1]), fmaxf(sv[0][qi][2], sv[0][qi][3]));
      float m1 = fmaxf(fmaxf(sv[1][qi][0], sv[1][qi][1]), fmaxf(sv[1][qi][2], sv[1][qi][3]));
      float m = fmaxf(m0, m1);
      m = fmaxf(m, __shfl_xor(m, 16));
      m = fmaxf(m, __shfl_xor(m, 32));
      mt[qi] = m;
    }
    if (g == 0) { mxS[kvh][32*qh + lr] = mt[0]; mxS[kvh][32*qh + 16 + lr] = mt[1]; }
    __syncthreads();   // B1: mxS published

    // E) cross-kvh max merge, running M/cor
    float cor[2];
#pragma unroll
    for (int qi = 0; qi < 2; ++qi) {
      float mo = mxS[1 - kvh][32*qh + 16*qi + lr];
      float Mn = fmaxf(M[qi], fmaxf(mt[qi], mo));
      cor[qi] = __expf(M[qi] - Mn);
      Sp[qi] *= cor[qi];
      M[qi] = Mn;
    }
    if (kvh == 0) {
      if (g == 0) { corS[32*qh + lr] = cor[0]; corS[32*qh + 16 + lr] = cor[1]; }
      int a = __all(cor[0] == 1.0f && cor[1] == 1.0f);
      if (lane == 0) flagS[qh] = a;
    }

    // F) P = exp(sv - M); Sp += P; store P*pm as bf16
#pragma unroll
    for (int kh = 0; kh < 2; ++kh) {
      float4 pm4 = *(const float4*)&pmS[cur][32*kvh + 16*kh + 4*g];
#pragma unroll
      for (int qi = 0; qi < 2; ++qi) {
        ushort4 pb;
#pragma unroll
        for (int r = 0; r < 4; ++r) {
          float p = __expf(sv[kh][qi][r] - M[qi]);
          Sp[qi] += p;
          ((ushort*)&pb)[r] = bf16_of(p * ((const float*)&pm4)[r]);
        }
        *(ushort4*)&Pb[(32*qh + 16*qi + lr)*72 + 32*kvh + 16*kh + 4*g] = pb;
      }
    }

    // G) write K(s+1) to alt buf (swizzled) + mask(s+1)
#pragma unroll
    for (int i = 0; i < 4; ++i) {
      const int Dc = i*512 + tid, row = Dc >> 5, c = Dc & 31;
      *(short8*)&Kbuf[nb][row*256 + ((c ^ (row & 7)) * 8)] = kreg[i];
    }
    if (tid < 64) { pmS[nb][tid] = mnv; lmS[nb][tid] = __logf(mnv + 1e-6f); }
    __syncthreads();   // B2: P, corS, flagS, K(s+1), mask(s+1) published

    // H) O rescale (skipped when no max moved) + PV
    const int skip = flagS[0] & flagS[1] & flagS[2] & flagS[3];
    if (!skip) {
#pragma unroll
      for (int rf = 0; rf < 8; ++rf) {
        float4 c4 = *(const float4*)&corS[16*rf + 4*g];
#pragma unroll
        for (int cf = 0; cf < 2; ++cf)
#pragma unroll
          for (int r = 0; r < 4; ++r)
            O[rf][cf][r] *= ((const float*)&c4)[r];
      }
    }
#pragma unroll
    for (int rf = 0; rf < 8; ++rf) {
      short8 pa0 = *(const short8*)&Pb[(16*rf + lr)*72 + 8*g];
      short8 pa1 = *(const short8*)&Pb[(16*rf + lr)*72 + 32 + 8*g];
#pragma unroll
      for (int cf = 0; cf < 2; ++cf) {
        O[rf][cf] = MFMA16(pa0, vf[cf][0], O[rf][cf], 0, 0, 0);
        O[rf][cf] = MFMA16(pa1, vf[cf][1], O[rf][cf], 0, 0, 0);
      }
    }
  }

  // ---- epilogue ----
#pragma unroll
  for (int qi = 0; qi < 2; ++qi) {
    Sp[qi] += __shfl_xor(Sp[qi], 16);
    Sp[qi] += __shfl_xor(Sp[qi], 32);
  }
  if (g == 0) { ssS[kvh][32*qh + lr] = Sp[0]; ssS[kvh][32*qh + 16 + lr] = Sp[1]; }
  __syncthreads();
  float SpT[2];
#pragma unroll
  for (int qi = 0; qi < 2; ++qi)
    SpT[qi] = Sp[qi] + ssS[1 - kvh][32*qh + 16*qi + lr];

  if (kvh == 0 && g == 0) {
    const size_t rowb = ((size_t)(ks*8 + b)) * L_ + q0 + 32*qh;
    Mstat[rowb + lr]      = M[0];  Sstat[rowb + lr]      = SpT[0];
    Mstat[rowb + 16 + lr] = M[1];  Sstat[rowb + 16 + lr] = SpT[1];
  }
#pragma unroll
  for (int rf = 0; rf < 8; ++rf) {
#pragma unroll
    for (int r = 0; r < 4; ++r) {
      const size_t row = ((size_t)(ks*8 + b)) * L_ + q0 + 16*rf + 4*g + r;
      float* op = &Opart[row * C_ + 32*wv];
#pragma unroll
      for (int cf = 0; cf < 2; ++cf) op[16*cf + lr] = O[rf][cf][r];
    }
  }
}

// ---------------------------------------------------------------------------
// Merge kv-splits, normalize, relu, split-bf16 -> hT (B,L,C).  (unchanged)
// ---------------------------------------------------------------------------
__global__ __launch_bounds__(256) void merge_kernel(
    const float* __restrict__ Opart, const float* __restrict__ Mstat,
    const float* __restrict__ Sstat,
    ushort* __restrict__ hTh, ushort* __restrict__ hTl)
{
  const int w = threadIdx.x >> 6, lane = threadIdx.x & 63;
  const size_t row = (size_t)blockIdx.x * 4 + w;
  const size_t n = (size_t)B_ * L_;
  const float M1 = Mstat[row],     M2 = Mstat[n + row];
  const float S1 = Sstat[row],     S2 = Sstat[n + row];
  const float M  = fmaxf(M1, M2);
  const float w1 = __expf(M1 - M), w2 = __expf(M2 - M);
  const float inv = 1.0f / (w1*S1 + w2*S2);
  float4 a = *(const float4*)&Opart[row * C_ + lane*4];
  float4 c = *(const float4*)&Opart[(n + row) * C_ + lane*4];
  float hv[4];
  hv[0] = fmaxf((w1*a.x + w2*c.x) * inv, 0.f);
  hv[1] = fmaxf((w1*a.y + w2*c.y) * inv, 0.f);
  hv[2] = fmaxf((w1*a.z + w2*c.z) * inv, 0.f);
  hv[3] = fmaxf((w1*a.w + w2*c.w) * inv, 0.f);
  ushort h[4], l[4];
#pragma unroll
  for (int j = 0; j < 4; ++j) split2(hv[j], h[j], l[j]);
  const size_t o = row * C_ + lane*4;
  *(ushort4*)&hTh[o] = make_ushort4(h[0], h[1], h[2], h[3]);
  *(ushort4*)&hTl[o] = make_ushort4(l[0], l[1], l[2], l[3]);
}

// ---------------------------------------------------------------------------
extern "C" void kernel_launch(void* const* d_in, const int* in_sizes, int n_in,
                              void* d_out, int out_size, void* d_ws, size_t ws_size,
                              hipStream_t stream) {
  (void)in_sizes; (void)n_in; (void)out_size; (void)ws_size;
  const float* x1   = (const float*)d_in[0];
  const float* mask = (const float*)d_in[2];
  const float* Wq   = (const float*)d_in[3];
  const float* bq   = (const float*)d_in[4];
  const float* Wk   = (const float*)d_in[5];
  const float* bk   = (const float*)d_in[6];
  const float* Wv   = (const float*)d_in[7];
  const float* bv   = (const float*)d_in[8];
  const float* Wo   = (const float*)d_in[9];
  const float* bo   = (const float*)d_in[10];
  float* out = (float*)d_out;
  uint8_t* w8 = (uint8_t*)d_ws;

  ushort* x1Th = (ushort*)(w8);                      // 16777216 B
  ushort* x1Tl = (ushort*)(w8 + 16777216);           // 16777216
  ushort* qTh  = (ushort*)(w8 + 33554432);           // 8388608 each
  ushort* qTl  = (ushort*)(w8 + 41943040);
  ushort* kTh  = (ushort*)(w8 + 50331648);
  ushort* kTl  = (ushort*)(w8 + 58720256);
  ushort* vh   = (ushort*)(w8 + 67108864);
  ushort* vl   = (ushort*)(w8 + 75497472);
  ushort* wb   = (ushort*)(w8 + 83886080);           // 2097152
  ushort* Wqh = wb;             ushort* Wql = wb + 131072;
  ushort* Wkh = wb + 262144;    ushort* Wkl = wb + 393216;
  ushort* Wvh = wb + 524288;    ushort* Wvl = wb + 655360;
  ushort* Woh = wb + 786432;    ushort* Wol = wb + 917504;
  float* Opart = (float*)(w8 + 85983232);            // 33554432
  float* Mstat = (float*)(w8 + 119537664);           // 131072
  float* Sstat = (float*)(w8 + 119668736);           // 131072
  ushort* hTh  = (ushort*)(w8 + 119799808);          // 8388608
  ushort* hTl  = (ushort*)(w8 + 128188416);          // 8388608

  // 1) x1 -> x1T split
  transpose_split_kernel<<<dim3(L_/32, D_/32, B_), 256, 0, stream>>>(x1, x1Th, x1Tl);
  // 2) weights split
  splitw_kernel<<<dim3(128, 1, 4), 256, 0, stream>>>(Wq, Wk, Wv, Wo, wb);
  // 3) qT = (x1T*Wq^T + bq) * 1/16   (L x C)
  mm_kernel<0><<<dim3(C_/128, L_/128, B_), 256, 0, stream>>>(
      x1Th, x1Tl, (long)L_*D_, D_, Wqh, Wql, 0, D_, D_,
      qTh, qTl, nullptr, (long)L_*C_, C_, bq, 0, nullptr, 0, 0.0625f);
  // 4) kT = x1T*Wk^T + bk
  mm_kernel<0><<<dim3(C_/128, L_/128, B_), 256, 0, stream>>>(
      x1Th, x1Tl, (long)L_*D_, D_, Wkh, Wkl, 0, D_, D_,
      kTh, kTl, nullptr, (long)L_*C_, C_, bk, 0, nullptr, 0, 1.0f);
  // 5) v = Wv*x1 + bv   (C x L)
  mm_kernel<1><<<dim3(L_/128, C_/128, B_), 256, 0, stream>>>(
      Wvh, Wvl, 0, D_, x1Th, x1Tl, (long)L_*D_, D_, D_,
      vh, vl, nullptr, (long)C_*L_, L_, bv, 0, nullptr, 0, 1.0f);
  // 6) flash attention v3 (single-bf16, 1 block/CU)
  flash_kernel<<<dim3(256), 512, 0, stream>>>(
      qTh, kTh, vh, mask, Opart, Mstat, Sstat);
  // 7) merge + normalize + relu + split
  merge_kernel<<<dim3(B_*L_/4), 256, 0, stream>>>(Opart, Mstat, Sstat, hTh, hTl);
  // 8) out = (Wo*relu(h) + bo) * mask
  mm_kernel<4><<<dim3(L_/128, D_/128, B_), 256, 0, stream>>>(
      Woh, Wol, 0, C_, hTh, hTl, (long)L_*C_, C_, C_,
      nullptr, nullptr, out, (long)D_*L_, L_, bo, 0, mask, L_, 1.0f);
}